// Round 8
// baseline (1568.794 us; speedup 1.0000x reference)
//
#include <hip/hip_runtime.h>

// ---------------------------------------------------------------------------
// DFTB layer, round 8.
//  K1 netvals / K2 rot / K3 coulomb / K4 erep  (unchanged)
//  K5 k_ns  : Newton-Schulz S^{-1/2}, 3 iters = 6 matmuls
//  K6 k_jac : one wave per molecule, __launch_bounds__(64,2) (known-good 128
//             VGPR). DS-pipe diet: plain-Givens one-sided Jacobi, 5 sweeps
//             (tol 1e-9); w=X*T / O=X*V / U=S*O read operands via wave-uniform
//             GLOBAL broadcasts (scalar path, off the DS pipe); only T=F*X
//             uses LDS broadcasts. ep via uniform global reads, not shfl.
// ---------------------------------------------------------------------------

#define NMOLC 2048
#define NSPC  500000
#define L0C   100000
#define NROTC 200000
#define NREPC 500000
#define MS 68   // LDS row stride for k_ns matmul buffers

// ---------------- K1: net_vals = A @ coeffs + b ----------------
__global__ __launch_bounds__(256) void k_netvals(const float* __restrict__ A,
                                                 const float* __restrict__ b,
                                                 const float* __restrict__ coeffs,
                                                 float* __restrict__ net){
  int gid = blockIdx.x * 256 + threadIdx.x;
  int row = gid >> 4;
  int l   = gid & 15;
  if (row >= NSPC) return;
  float4 c4 = reinterpret_cast<const float4*>(coeffs)[l];
  float4 a4 = reinterpret_cast<const float4*>(A)[(size_t)row * 16 + l];
  float s = a4.x*c4.x + a4.y*c4.y + a4.z*c4.z + a4.w*c4.w;
  s += __shfl_xor(s, 1, 16);
  s += __shfl_xor(s, 2, 16);
  s += __shfl_xor(s, 4, 16);
  s += __shfl_xor(s, 8, 16);
  if (l == 0) net[row] = s + b[row];
}

// ---------------- K2: rot_out = [0,1] ++ direct ++ rotated ----------------
__global__ __launch_bounds__(256) void k_rot(const float* __restrict__ net,
                                             const float* __restrict__ rot_tensor,
                                             const int* __restrict__ g_rot_direct,
                                             const int* __restrict__ g_rot,
                                             float* __restrict__ rot_out){
  int gid = blockIdx.x * 256 + threadIdx.x;
  if (gid == 0){ rot_out[0] = 0.f; rot_out[1] = 1.f; }
  if (gid < L0C){
    rot_out[2 + gid] = net[g_rot_direct[gid]];
  }
  int n = gid - L0C;
  if (n >= 0 && n < NROTC){
    float v0 = net[g_rot[3*n    ]];
    float v1 = net[g_rot[3*n + 1]];
    float v2 = net[g_rot[3*n + 2]];
    const float* R = rot_tensor + (size_t)9 * n;
    float* o = rot_out + 2 + L0C + 3*n;
    o[0] = R[0]*v0 + R[1]*v1 + R[2]*v2;
    o[1] = R[3]*v0 + R[4]*v1 + R[5]*v2;
    o[2] = R[6]*v0 + R[7]*v1 + R[8]*v2;
  }
}

// ---------------- K3: dQ, ep = G@dQ, ener2; zero erep ----------------
__global__ __launch_bounds__(256) void k_coulomb(const float* __restrict__ S,
                                                 const float* __restrict__ G,
                                                 const float* __restrict__ rho,
                                                 const float* __restrict__ qneutral,
                                                 float* __restrict__ ep_all,
                                                 float* __restrict__ ener2_a,
                                                 float* __restrict__ erep_a){
  __shared__ float sRed[256];
  __shared__ float sdQ[64];
  __shared__ float sEp[64];
  const int mol = blockIdx.x;
  const int t = threadIdx.x;
  const int i = t >> 2, q4 = t & 3;
  const float* Sm = S   + (size_t)mol * 4096;
  const float* Gm = G   + (size_t)mol * 4096;
  const float* Rm = rho + (size_t)mol * 4096;

  float acc = 0.f;
  {
    const float4* S4 = reinterpret_cast<const float4*>(Sm + i*64 + q4*16);
    const float4* R4 = reinterpret_cast<const float4*>(Rm + i*64 + q4*16);
    #pragma unroll
    for (int m = 0; m < 4; ++m){
      float4 sv = S4[m], rv = R4[m];
      acc += sv.x*rv.x + sv.y*rv.y + sv.z*rv.z + sv.w*rv.w;
    }
  }
  sRed[t] = acc; __syncthreads();
  if (t < 64) sdQ[t] = qneutral[(size_t)mol*64 + t]
                       - (sRed[4*t] + sRed[4*t+1] + sRed[4*t+2] + sRed[4*t+3]);
  __syncthreads();

  float acc2 = 0.f;
  {
    const float4* G4 = reinterpret_cast<const float4*>(Gm + i*64 + q4*16);
    #pragma unroll
    for (int m = 0; m < 4; ++m){
      float4 gv = G4[m];
      int j0 = q4*16 + m*4;
      acc2 += gv.x*sdQ[j0] + gv.y*sdQ[j0+1] + gv.z*sdQ[j0+2] + gv.w*sdQ[j0+3];
    }
  }
  sRed[t] = acc2; __syncthreads();
  if (t < 64){
    float e = sRed[4*t] + sRed[4*t+1] + sRed[4*t+2] + sRed[4*t+3];
    sEp[t] = e;
    ep_all[(size_t)mol*64 + t] = e;
  }
  __syncthreads();
  if (t == 0){
    float s = 0.f;
    for (int j = 0; j < 64; ++j) s += sdQ[j] * sEp[j];
    ener2_a[mol] = 0.5f * s;
    erep_a[mol]  = 0.f;
  }
}

// ---------------- K4: Erep segment sum (sorted seg ids) ----------------
__global__ __launch_bounds__(256) void k_erep(const float* __restrict__ net,
                                              const int* __restrict__ g_rep,
                                              const int* __restrict__ seg_ids,
                                              float* __restrict__ erep_a){
  const int CH = 64;
  long tid = (long)blockIdx.x * 256 + threadIdx.x;
  long start = tid * CH;
  if (start >= NREPC) return;
  long end = start + CH; if (end > NREPC) end = NREPC;
  int cur = seg_ids[start];
  float acc = 0.f;
  for (long e = start; e < end; ++e){
    int sgid = seg_ids[e];
    if (sgid != cur){ atomicAdd(&erep_a[cur], acc); cur = sgid; acc = 0.f; }
    acc += net[g_rep[e]];
  }
  atomicAdd(&erep_a[cur], acc);
}

// ---------------- LDS matmul helper (64x64, stride MS), A symmetric ------
__device__ __forceinline__ void mm_symA(float (*__restrict__ D)[MS],
                                        const float (*__restrict__ A)[MS],
                                        const float (*__restrict__ B)[MS],
                                        float alpha, float diag, int t){
  const int r0 = (t & 15) << 2, c0 = (t >> 4) << 2;
  float acc[4][4];
  #pragma unroll
  for (int i = 0; i < 4; ++i)
    #pragma unroll
    for (int j = 0; j < 4; ++j) acc[i][j] = 0.f;
  #pragma unroll 8
  for (int k = 0; k < 64; ++k){
    float4 av = *reinterpret_cast<const float4*>(&A[k][r0]);
    float4 bv = *reinterpret_cast<const float4*>(&B[k][c0]);
    float a_[4] = {av.x, av.y, av.z, av.w};
    float b_[4] = {bv.x, bv.y, bv.z, bv.w};
    #pragma unroll
    for (int i = 0; i < 4; ++i)
      #pragma unroll
      for (int j = 0; j < 4; ++j)
        acc[i][j] += a_[i] * b_[j];
  }
  #pragma unroll
  for (int i = 0; i < 4; ++i)
    #pragma unroll
    for (int j = 0; j < 4; ++j)
      D[r0+i][c0+j] = alpha * acc[i][j] + ((r0+i) == (c0+j) ? diag : 0.f);
}

// ---------------- K5: Newton-Schulz -> X = S^{-1/2} (3 iters, 6 mm) ------
__global__ __launch_bounds__(256, 2) void k_ns(const float* __restrict__ S,
                                               float* __restrict__ X_all){
  __shared__ float M[4][64][MS];
  const int t   = threadIdx.x;
  const int mol = blockIdx.x;
  const float* Sm = S + (size_t)mol * 4096;

  // init: M0 = S, M2 = 3I - S
  #pragma unroll
  for (int m = 0; m < 16; ++m){
    int e = t + (m << 8);
    int i = e >> 6, j = e & 63;
    float s = Sm[e];
    M[0][i][j] = s;
    M[2][i][j] = ((i == j) ? 3.f : 0.f) - s;
  }
  __syncthreads();
  mm_symA(M[3], M[0], M[2], 0.5f, 0.f, t);          // Y1 = 0.5 S (3I-S)
  #pragma unroll
  for (int m = 0; m < 16; ++m){
    int e = t + (m << 8);
    M[1][e >> 6][e & 63] = 0.5f * M[2][e >> 6][e & 63];  // Z1 = 0.5(3I-S)
  }
  __syncthreads();
  // iter2: Y=M3, Z=M1
  mm_symA(M[0], M[1], M[3], -1.f, 3.f, t); __syncthreads();  // T2 = 3I - Z1*Y1
  mm_symA(M[2], M[3], M[0], 0.5f, 0.f, t); __syncthreads();  // Y2 = 0.5*Y1*T2
  mm_symA(M[3], M[0], M[1], 0.5f, 0.f, t); __syncthreads();  // Z2 = 0.5*T2*Z1
  // iter3 (Z-only): Y=M2, Z=M3
  mm_symA(M[1], M[3], M[2], -1.f, 3.f, t); __syncthreads();  // T3 = 3I - Z2*Y2
  mm_symA(M[0], M[1], M[3], 0.5f, 0.f, t); __syncthreads();  // X  = 0.5*T3*Z2

  #pragma unroll
  for (int m = 0; m < 16; ++m){
    int e = t + (m << 8);
    X_all[(size_t)mol * 4096 + e] = M[0][e >> 6][e & 63];
  }
}

// ---------------- K6: one-wave fockp + one-sided Jacobi (DS-diet) --------
__global__ __launch_bounds__(64, 2)
void k_jac(const float* __restrict__ S,
           const float* __restrict__ X_all,
           const int* __restrict__ g_oper,
           const float* __restrict__ rot_out,
           const float* __restrict__ ep_all,
           const float* __restrict__ ener2_a,
           const float* __restrict__ erep_a,
           float* __restrict__ out){
  __shared__ float B[64 * 68];          // staging buffer (H transpose, then F)
  const int lane = threadIdx.x;
  const int mol  = blockIdx.x;
  const float* Xm  = X_all + (size_t)mol * 4096;
  const float* Sm  = S     + (size_t)mol * 4096;
  const int*   gm  = g_oper + (size_t)mol * 4096;
  const float* epg = ep_all + (size_t)mol * 64;
  const float  epl = epg[lane];

  // --- H gather into regs + LDS (stride 65) for transpose access ---
  float h[64];
  #pragma unroll
  for (int i = 0; i < 64; ++i){
    float v = rot_out[gm[i*64 + lane]];
    h[i] = v;
    B[i*65 + lane] = v;
  }
  __syncthreads();
  // F column: f[i] = 0.5(H_ij + H_ji) - 0.5 S_ij (ep_i + ep_j); ep_i uniform
  #pragma unroll
  for (int i = 0; i < 64; ++i){
    float hji = B[lane*65 + i];
    h[i] = 0.5f*(h[i] + hji) - 0.5f*Sm[i*64 + lane]*(epg[i] + epl);
  }
  __syncthreads();
  // stage F row-major (stride 68, float4-aligned rows)
  #pragma unroll
  for (int i = 0; i < 64; ++i) B[i*68 + lane] = h[i];
  __syncthreads();

  // --- T = F*X: tt[i] = sum_k F[i][k] * x[k]  (F via LDS broadcast) ---
  float x[64];
  #pragma unroll
  for (int i = 0; i < 64; ++i) x[i] = Xm[i*64 + lane];
  float tt[64];
  #pragma unroll 8
  for (int i = 0; i < 64; ++i){
    float acc = 0.f;
    #pragma unroll
    for (int k = 0; k < 64; k += 4){
      float4 fv = *reinterpret_cast<const float4*>(&B[i*68 + k]);
      acc = fmaf(fv.x, x[k], acc);   acc = fmaf(fv.y, x[k+1], acc);
      acc = fmaf(fv.z, x[k+2], acc); acc = fmaf(fv.w, x[k+3], acc);
    }
    tt[i] = acc;
  }

  // --- w = X*T: X rows via wave-uniform GLOBAL broadcast (off DS pipe) ---
  float w[64];
  #pragma unroll 8
  for (int i = 0; i < 64; ++i){
    float acc = 0.f;
    #pragma unroll
    for (int k = 0; k < 64; k += 4){
      float4 xv = *reinterpret_cast<const float4*>(Xm + i*64 + k);
      acc = fmaf(xv.x, tt[k], acc);   acc = fmaf(xv.y, tt[k+1], acc);
      acc = fmaf(xv.z, tt[k+2], acc); acc = fmaf(xv.w, tt[k+3], acc);
    }
    w[i] = acc;
  }

  // --- Gershgorin shift (PD): mu = 1.02 * max col abs-sum ---
  float c0s = 0.f, c1s = 0.f, c2s = 0.f, c3s = 0.f;
  #pragma unroll
  for (int i = 0; i < 64; i += 4){
    c0s += fabsf(w[i]);   c1s += fabsf(w[i+1]);
    c2s += fabsf(w[i+2]); c3s += fabsf(w[i+3]);
  }
  float mu = (c0s + c1s) + (c2s + c3s);
  #pragma unroll
  for (int d2 = 1; d2 < 64; d2 <<= 1) mu = fmaxf(mu, __shfl_xor(mu, d2));
  mu *= 1.02f;
  #pragma unroll
  for (int i = 0; i < 64; ++i) w[i] += (i == lane) ? mu : 0.f;

  // --- one-sided Jacobi, plain Givens, partner cached, 5 sweeps ---
  for (int sweep = 0; sweep < 5; ++sweep){
    float a0 = 0.f, a1 = 0.f, a2 = 0.f, a3 = 0.f;
    #pragma unroll
    for (int i = 0; i < 64; i += 4){
      a0 = fmaf(w[i],   w[i],   a0); a1 = fmaf(w[i+1], w[i+1], a1);
      a2 = fmaf(w[i+2], w[i+2], a2); a3 = fmaf(w[i+3], w[i+3], a3);
    }
    float alpha = (a0 + a1) + (a2 + a3);   // ||col||^2, refreshed per sweep

    unsigned long long any = 0ULL;
    for (int r = 0; r < 63; ++r){
      int part = (lane == 63) ? r : ((lane == r) ? 63 : ((2*r - lane + 126) % 63));
      float pw[64];
      float g0 = 0.f, g1 = 0.f, g2 = 0.f, g3 = 0.f;
      #pragma unroll
      for (int i = 0; i < 64; i += 4){
        pw[i]   = __shfl(w[i],   part);
        pw[i+1] = __shfl(w[i+1], part);
        pw[i+2] = __shfl(w[i+2], part);
        pw[i+3] = __shfl(w[i+3], part);
        g0 = fmaf(w[i],   pw[i],   g0);
        g1 = fmaf(w[i+1], pw[i+1], g1);
        g2 = fmaf(w[i+2], pw[i+2], g2);
        g3 = fmaf(w[i+3], pw[i+3], g3);
      }
      float gamma = (g0 + g1) + (g2 + g3);
      float beta  = __shfl(alpha, part);
      bool isp = lane < part;
      float ap = isp ? alpha : beta;
      float aq = isp ? beta  : alpha;
      bool rot = (gamma * gamma) > (1e-9f * ap * aq);
      unsigned long long bal = __ballot(rot);
      any |= bal;
      if (bal == 0ULL) continue;
      float tau = (aq - ap) / (2.f * gamma);
      float tq  = copysignf(1.f, tau) / (fabsf(tau) + sqrtf(fmaf(tau, tau, 1.f)));
      float c = rsqrtf(fmaf(tq, tq, 1.f));
      float s = tq * c;
      if (!rot){ c = 1.f; s = 0.f; }
      float bc = isp ? -s : s;
      alpha = c*c*alpha + s*s*beta + 2.f*c*bc*gamma;
      #pragma unroll
      for (int i = 0; i < 64; ++i)
        w[i] = fmaf(bc, pw[i], c * w[i]);
    }
    if (any == 0ULL) break;
  }

  // --- lambda = ||w|| - mu; ranks; Eorb; v = w * (occ/||w||) ---
  float n0 = 0.f, n1 = 0.f, n2 = 0.f, n3 = 0.f;
  #pragma unroll
  for (int i = 0; i < 64; i += 4){
    n0 = fmaf(w[i],   w[i],   n0); n1 = fmaf(w[i+1], w[i+1], n1);
    n2 = fmaf(w[i+2], w[i+2], n2); n3 = fmaf(w[i+3], w[i+3], n3);
  }
  float lamS = sqrtf((n0 + n1) + (n2 + n3));
  float lam  = lamS - mu;
  int rank = 0;
  for (int k = 0; k < 64; ++k){
    float lk = __shfl(lam, k);
    rank += (lk < lam || (lk == lam && k < lane)) ? 1 : 0;
  }
  out[(size_t)mol*65 + 1 + rank] = lam;

  float occf = (rank < 32) ? 1.f : 0.f;
  float slam = occf * lam;
  #pragma unroll
  for (int d2 = 1; d2 < 64; d2 <<= 1) slam += __shfl_xor(slam, d2);

  float scale = occf / lamS;
  #pragma unroll
  for (int i = 0; i < 64; ++i) w[i] *= scale;   // w := v_occ column

  // --- O = X * V_occ  (X rows via global broadcast) ---
  float o[64];
  #pragma unroll 8
  for (int i = 0; i < 64; ++i){
    float acc = 0.f;
    #pragma unroll
    for (int k = 0; k < 64; k += 4){
      float4 xv = *reinterpret_cast<const float4*>(Xm + i*64 + k);
      acc = fmaf(xv.x, w[k], acc);   acc = fmaf(xv.y, w[k+1], acc);
      acc = fmaf(xv.z, w[k+2], acc); acc = fmaf(xv.w, w[k+3], acc);
    }
    o[i] = acc;
  }
  // --- U = S * O  (S rows via global broadcast) ---
  float u2[64];
  #pragma unroll 8
  for (int i = 0; i < 64; ++i){
    float acc = 0.f;
    #pragma unroll
    for (int k = 0; k < 64; k += 4){
      float4 sv = *reinterpret_cast<const float4*>(Sm + i*64 + k);
      acc = fmaf(sv.x, o[k], acc);   acc = fmaf(sv.y, o[k+1], acc);
      acc = fmaf(sv.z, o[k+2], acc); acc = fmaf(sv.w, o[k+3], acc);
    }
    u2[i] = acc;
  }
  // --- ener1 = 2*sum(lam_occ) + 2*sum_ik ep_i O_ik U_ik ---
  float t0 = 0.f, t1 = 0.f, t2 = 0.f, t3 = 0.f;
  #pragma unroll
  for (int i = 0; i < 64; i += 4){
    t0 = fmaf(epg[i],   o[i]  *u2[i],   t0);
    t1 = fmaf(epg[i+1], o[i+1]*u2[i+1], t1);
    t2 = fmaf(epg[i+2], o[i+2]*u2[i+2], t2);
    t3 = fmaf(epg[i+3], o[i+3]*u2[i+3], t3);
  }
  float term = (t0 + t1) + (t2 + t3);
  #pragma unroll
  for (int d2 = 1; d2 < 64; d2 <<= 1) term += __shfl_xor(term, d2);

  if (lane == 0){
    out[(size_t)mol*65] = 2.f*slam + 2.f*term + ener2_a[mol] + erep_a[mol];
  }
}

// ---------------------------------------------------------------------------
extern "C" void kernel_launch(void* const* d_in, const int* in_sizes, int n_in,
                              void* d_out, int out_size, void* d_ws, size_t ws_size,
                              hipStream_t stream){
  (void)in_sizes; (void)n_in; (void)out_size; (void)ws_size;
  const float* A          = (const float*)d_in[0];
  const float* b          = (const float*)d_in[1];
  const float* coeffs     = (const float*)d_in[2];
  const float* rot_tensor = (const float*)d_in[3];
  const float* S          = (const float*)d_in[4];
  const float* G          = (const float*)d_in[5];
  const float* rho        = (const float*)d_in[6];
  const float* qneutral   = (const float*)d_in[7];
  const int* g_rot_direct = (const int*)d_in[9];
  const int* g_rot        = (const int*)d_in[10];
  const int* g_oper       = (const int*)d_in[11];
  const int* g_rep        = (const int*)d_in[12];
  const int* seg_ids      = (const int*)d_in[13];
  float* out = (float*)d_out;

  float* W       = (float*)d_ws;
  float* net     = W;                    // 500000
  float* rot_out = W + 500000;           // 700002 (padded to 700004)
  float* ep_all  = W + 1200004;          // 2048*64
  float* ener2_a = W + 1331076;          // 2048
  float* erep_a  = W + 1333124;          // 2048
  float* X_all   = W + 1335172;          // 2048*4096

  k_netvals<<<(NSPC*16)/256, 256, 0, stream>>>(A, b, coeffs, net);
  k_rot<<<(L0C + NROTC + 255)/256, 256, 0, stream>>>(net, rot_tensor, g_rot_direct, g_rot, rot_out);
  k_coulomb<<<NMOLC, 256, 0, stream>>>(S, G, rho, qneutral, ep_all, ener2_a, erep_a);
  k_erep<<<((NREPC + 63)/64 + 255)/256, 256, 0, stream>>>(net, g_rep, seg_ids, erep_a);
  k_ns<<<NMOLC, 256, 0, stream>>>(S, X_all);
  k_jac<<<NMOLC, 64, 0, stream>>>(S, X_all, g_oper, rot_out, ep_all, ener2_a, erep_a, out);
}

// Round 9
// 883.222 us; speedup vs baseline: 1.7762x; 1.7762x over previous
//
#include <hip/hip_runtime.h>

// ---------------------------------------------------------------------------
// DFTB layer, round 9.
//  K1 netvals / K2 rot / K3 coulomb / K4 erep  (unchanged)
//  K5 k_ns  : Newton-Schulz S^{-1/2}, 3 iters = 6 matmuls (validated r7/r8)
//  K6 k_jac : BYTE-EXACT revert to the round-6-measured structure (128 VGPR,
//             zero hot-loop spill, LDS-broadcast matmuls, X staged in LDS),
//             with exactly two constant changes validated in r7/r8:
//               * rotation tol 1e-12 -> 1e-9
//               * sweep cap 8 -> 5
//             r7 (fast-Givens + waves_per_eu) and r8 (global-broadcast)
//             both triggered 96-VGPR allocations + GB-scale spill; do NOT
//             deviate from this structure without -Rpass-analysis evidence.
// ---------------------------------------------------------------------------

#define NMOLC 2048
#define NSPC  500000
#define L0C   100000
#define NROTC 200000
#define NREPC 500000
#define MS 68   // LDS row stride for k_ns matmul buffers

// ---------------- K1: net_vals = A @ coeffs + b ----------------
__global__ __launch_bounds__(256) void k_netvals(const float* __restrict__ A,
                                                 const float* __restrict__ b,
                                                 const float* __restrict__ coeffs,
                                                 float* __restrict__ net){
  int gid = blockIdx.x * 256 + threadIdx.x;
  int row = gid >> 4;
  int l   = gid & 15;
  if (row >= NSPC) return;
  float4 c4 = reinterpret_cast<const float4*>(coeffs)[l];
  float4 a4 = reinterpret_cast<const float4*>(A)[(size_t)row * 16 + l];
  float s = a4.x*c4.x + a4.y*c4.y + a4.z*c4.z + a4.w*c4.w;
  s += __shfl_xor(s, 1, 16);
  s += __shfl_xor(s, 2, 16);
  s += __shfl_xor(s, 4, 16);
  s += __shfl_xor(s, 8, 16);
  if (l == 0) net[row] = s + b[row];
}

// ---------------- K2: rot_out = [0,1] ++ direct ++ rotated ----------------
__global__ __launch_bounds__(256) void k_rot(const float* __restrict__ net,
                                             const float* __restrict__ rot_tensor,
                                             const int* __restrict__ g_rot_direct,
                                             const int* __restrict__ g_rot,
                                             float* __restrict__ rot_out){
  int gid = blockIdx.x * 256 + threadIdx.x;
  if (gid == 0){ rot_out[0] = 0.f; rot_out[1] = 1.f; }
  if (gid < L0C){
    rot_out[2 + gid] = net[g_rot_direct[gid]];
  }
  int n = gid - L0C;
  if (n >= 0 && n < NROTC){
    float v0 = net[g_rot[3*n    ]];
    float v1 = net[g_rot[3*n + 1]];
    float v2 = net[g_rot[3*n + 2]];
    const float* R = rot_tensor + (size_t)9 * n;
    float* o = rot_out + 2 + L0C + 3*n;
    o[0] = R[0]*v0 + R[1]*v1 + R[2]*v2;
    o[1] = R[3]*v0 + R[4]*v1 + R[5]*v2;
    o[2] = R[6]*v0 + R[7]*v1 + R[8]*v2;
  }
}

// ---------------- K3: dQ, ep = G@dQ, ener2; zero erep ----------------
__global__ __launch_bounds__(256) void k_coulomb(const float* __restrict__ S,
                                                 const float* __restrict__ G,
                                                 const float* __restrict__ rho,
                                                 const float* __restrict__ qneutral,
                                                 float* __restrict__ ep_all,
                                                 float* __restrict__ ener2_a,
                                                 float* __restrict__ erep_a){
  __shared__ float sRed[256];
  __shared__ float sdQ[64];
  __shared__ float sEp[64];
  const int mol = blockIdx.x;
  const int t = threadIdx.x;
  const int i = t >> 2, q4 = t & 3;
  const float* Sm = S   + (size_t)mol * 4096;
  const float* Gm = G   + (size_t)mol * 4096;
  const float* Rm = rho + (size_t)mol * 4096;

  float acc = 0.f;
  {
    const float4* S4 = reinterpret_cast<const float4*>(Sm + i*64 + q4*16);
    const float4* R4 = reinterpret_cast<const float4*>(Rm + i*64 + q4*16);
    #pragma unroll
    for (int m = 0; m < 4; ++m){
      float4 sv = S4[m], rv = R4[m];
      acc += sv.x*rv.x + sv.y*rv.y + sv.z*rv.z + sv.w*rv.w;
    }
  }
  sRed[t] = acc; __syncthreads();
  if (t < 64) sdQ[t] = qneutral[(size_t)mol*64 + t]
                       - (sRed[4*t] + sRed[4*t+1] + sRed[4*t+2] + sRed[4*t+3]);
  __syncthreads();

  float acc2 = 0.f;
  {
    const float4* G4 = reinterpret_cast<const float4*>(Gm + i*64 + q4*16);
    #pragma unroll
    for (int m = 0; m < 4; ++m){
      float4 gv = G4[m];
      int j0 = q4*16 + m*4;
      acc2 += gv.x*sdQ[j0] + gv.y*sdQ[j0+1] + gv.z*sdQ[j0+2] + gv.w*sdQ[j0+3];
    }
  }
  sRed[t] = acc2; __syncthreads();
  if (t < 64){
    float e = sRed[4*t] + sRed[4*t+1] + sRed[4*t+2] + sRed[4*t+3];
    sEp[t] = e;
    ep_all[(size_t)mol*64 + t] = e;
  }
  __syncthreads();
  if (t == 0){
    float s = 0.f;
    for (int j = 0; j < 64; ++j) s += sdQ[j] * sEp[j];
    ener2_a[mol] = 0.5f * s;
    erep_a[mol]  = 0.f;
  }
}

// ---------------- K4: Erep segment sum (sorted seg ids) ----------------
__global__ __launch_bounds__(256) void k_erep(const float* __restrict__ net,
                                              const int* __restrict__ g_rep,
                                              const int* __restrict__ seg_ids,
                                              float* __restrict__ erep_a){
  const int CH = 64;
  long tid = (long)blockIdx.x * 256 + threadIdx.x;
  long start = tid * CH;
  if (start >= NREPC) return;
  long end = start + CH; if (end > NREPC) end = NREPC;
  int cur = seg_ids[start];
  float acc = 0.f;
  for (long e = start; e < end; ++e){
    int sgid = seg_ids[e];
    if (sgid != cur){ atomicAdd(&erep_a[cur], acc); cur = sgid; acc = 0.f; }
    acc += net[g_rep[e]];
  }
  atomicAdd(&erep_a[cur], acc);
}

// ---------------- LDS matmul helper (64x64, stride MS), A symmetric ------
__device__ __forceinline__ void mm_symA(float (*__restrict__ D)[MS],
                                        const float (*__restrict__ A)[MS],
                                        const float (*__restrict__ B)[MS],
                                        float alpha, float diag, int t){
  const int r0 = (t & 15) << 2, c0 = (t >> 4) << 2;
  float acc[4][4];
  #pragma unroll
  for (int i = 0; i < 4; ++i)
    #pragma unroll
    for (int j = 0; j < 4; ++j) acc[i][j] = 0.f;
  #pragma unroll 8
  for (int k = 0; k < 64; ++k){
    float4 av = *reinterpret_cast<const float4*>(&A[k][r0]);
    float4 bv = *reinterpret_cast<const float4*>(&B[k][c0]);
    float a_[4] = {av.x, av.y, av.z, av.w};
    float b_[4] = {bv.x, bv.y, bv.z, bv.w};
    #pragma unroll
    for (int i = 0; i < 4; ++i)
      #pragma unroll
      for (int j = 0; j < 4; ++j)
        acc[i][j] += a_[i] * b_[j];
  }
  #pragma unroll
  for (int i = 0; i < 4; ++i)
    #pragma unroll
    for (int j = 0; j < 4; ++j)
      D[r0+i][c0+j] = alpha * acc[i][j] + ((r0+i) == (c0+j) ? diag : 0.f);
}

// ---------------- K5: Newton-Schulz -> X = S^{-1/2} (3 iters, 6 mm) ------
__global__ __launch_bounds__(256, 2) void k_ns(const float* __restrict__ S,
                                               float* __restrict__ X_all){
  __shared__ float M[4][64][MS];
  const int t   = threadIdx.x;
  const int mol = blockIdx.x;
  const float* Sm = S + (size_t)mol * 4096;

  // init: M0 = S, M2 = 3I - S
  #pragma unroll
  for (int m = 0; m < 16; ++m){
    int e = t + (m << 8);
    int i = e >> 6, j = e & 63;
    float s = Sm[e];
    M[0][i][j] = s;
    M[2][i][j] = ((i == j) ? 3.f : 0.f) - s;
  }
  __syncthreads();
  mm_symA(M[3], M[0], M[2], 0.5f, 0.f, t);          // Y1 = 0.5 S (3I-S)
  #pragma unroll
  for (int m = 0; m < 16; ++m){
    int e = t + (m << 8);
    M[1][e >> 6][e & 63] = 0.5f * M[2][e >> 6][e & 63];  // Z1 = 0.5(3I-S)
  }
  __syncthreads();
  // iter2: Y=M3, Z=M1
  mm_symA(M[0], M[1], M[3], -1.f, 3.f, t); __syncthreads();  // T2 = 3I - Z1*Y1
  mm_symA(M[2], M[3], M[0], 0.5f, 0.f, t); __syncthreads();  // Y2 = 0.5*Y1*T2
  mm_symA(M[3], M[0], M[1], 0.5f, 0.f, t); __syncthreads();  // Z2 = 0.5*T2*Z1
  // iter3 (Z-only): Y=M2, Z=M3
  mm_symA(M[1], M[3], M[2], -1.f, 3.f, t); __syncthreads();  // T3 = 3I - Z2*Y2
  mm_symA(M[0], M[1], M[3], 0.5f, 0.f, t); __syncthreads();  // X  = 0.5*T3*Z2

  #pragma unroll
  for (int m = 0; m < 16; ++m){
    int e = t + (m << 8);
    X_all[(size_t)mol * 4096 + e] = M[0][e >> 6][e & 63];
  }
}

// ---------------- K6: one-wave fockp + V-free one-sided Jacobi -----------
// (r6-measured structure: 128 VGPR, no hot-loop spill. Only the tolerance
//  and sweep-cap constants differ from the round-6 binary.)
__global__ __launch_bounds__(64, 2) void k_jac(const float* __restrict__ S,
                                               const float* __restrict__ X_all,
                                               const int* __restrict__ g_oper,
                                               const float* __restrict__ rot_out,
                                               const float* __restrict__ ep_all,
                                               const float* __restrict__ ener2_a,
                                               const float* __restrict__ erep_a,
                                               float* __restrict__ out){
  __shared__ float B[64 * 68];          // one staging buffer, reused
  const int lane = threadIdx.x;
  const int mol  = blockIdx.x;
  const float* Xm = X_all + (size_t)mol * 4096;
  const float* Sm = S     + (size_t)mol * 4096;
  const int*   gm = g_oper + (size_t)mol * 4096;
  const float  epl = ep_all[(size_t)mol*64 + lane];

  // --- H gather (stride 65: transpose read is 2-way -> free) ---
  float h[64];
  #pragma unroll
  for (int i = 0; i < 64; ++i){
    float v = rot_out[gm[i*64 + lane]];
    h[i] = v;
    B[i*65 + lane] = v;
  }
  __syncthreads();
  // F column: f[i] = 0.5(H_ij + H_ji) - 0.5 S_ij (ep_i + ep_j)
  #pragma unroll
  for (int i = 0; i < 64; ++i){
    float hji = B[lane*65 + i];
    float epi = __shfl(epl, i);
    h[i] = 0.5f*(h[i] + hji) - 0.5f*Sm[i*64 + lane]*(epi + epl);
  }
  __syncthreads();
  // stage F (stride 68, float4-aligned rows for broadcast b128 reads)
  #pragma unroll
  for (int i = 0; i < 64; ++i) B[i*68 + lane] = h[i];
  __syncthreads();

  // --- T = F*X: tt[i] = sum_k F[i][k] * x[k], F broadcast from LDS ---
  float x[64];
  #pragma unroll
  for (int i = 0; i < 64; ++i) x[i] = Xm[i*64 + lane];
  float tt[64];
  #pragma unroll
  for (int i = 0; i < 64; ++i){
    float acc = 0.f;
    #pragma unroll
    for (int k = 0; k < 64; k += 4){
      float4 fv = *reinterpret_cast<const float4*>(&B[i*68 + k]);
      acc = fmaf(fv.x, x[k], acc);   acc = fmaf(fv.y, x[k+1], acc);
      acc = fmaf(fv.z, x[k+2], acc); acc = fmaf(fv.w, x[k+3], acc);
    }
    tt[i] = acc;
  }
  __syncthreads();
  // stage X (kept resident in LDS through Jacobi for the epilogue)
  #pragma unroll
  for (int i = 0; i < 64; ++i) B[i*68 + lane] = x[i];
  __syncthreads();

  // --- w = X*T (fockp column) ---
  float w[64];
  #pragma unroll
  for (int i = 0; i < 64; ++i){
    float acc = 0.f;
    #pragma unroll
    for (int k = 0; k < 64; k += 4){
      float4 xv = *reinterpret_cast<const float4*>(&B[i*68 + k]);
      acc = fmaf(xv.x, tt[k], acc);   acc = fmaf(xv.y, tt[k+1], acc);
      acc = fmaf(xv.z, tt[k+2], acc); acc = fmaf(xv.w, tt[k+3], acc);
    }
    w[i] = acc;
  }

  // --- Gershgorin shift (PD): mu = 1.02 * max col abs-sum ---
  float csum = 0.f;
  #pragma unroll
  for (int i = 0; i < 64; ++i) csum += fabsf(w[i]);
  float mu = csum;
  #pragma unroll
  for (int d = 1; d < 64; d <<= 1) mu = fmaxf(mu, __shfl_xor(mu, d));
  mu *= 1.02f;
  #pragma unroll
  for (int i = 0; i < 64; ++i) w[i] += (i == lane) ? mu : 0.f;

  // --- one-sided Jacobi, V-free, partner column cached ---
  for (int sweep = 0; sweep < 5; ++sweep){
    float alpha = 0.f;
    #pragma unroll
    for (int i = 0; i < 64; ++i) alpha = fmaf(w[i], w[i], alpha);
    unsigned long long any = 0ULL;
    for (int r = 0; r < 63; ++r){
      int part = (lane == 63) ? r : ((lane == r) ? 63 : ((2*r - lane + 126) % 63));
      float pw[64];
      float gamma = 0.f;
      #pragma unroll
      for (int i = 0; i < 64; ++i){
        pw[i] = __shfl(w[i], part);
        gamma = fmaf(w[i], pw[i], gamma);
      }
      float beta = __shfl(alpha, part);
      bool isp = lane < part;
      float ap = isp ? alpha : beta;
      float aq = isp ? beta  : alpha;
      bool rot = (gamma * gamma) > (1e-9f * ap * aq);
      unsigned long long bal = __ballot(rot);
      any |= bal;
      if (bal == 0ULL) continue;
      float tau = (aq - ap) / (2.f * gamma);
      float tq  = copysignf(1.f, tau) / (fabsf(tau) + sqrtf(fmaf(tau, tau, 1.f)));
      float c = rsqrtf(fmaf(tq, tq, 1.f));
      float s = tq * c;
      if (!rot){ c = 1.f; s = 0.f; }
      float bcoef = isp ? -s : s;
      alpha = c*c*alpha + s*s*beta + 2.f*c*bcoef*gamma;
      #pragma unroll
      for (int i = 0; i < 64; ++i)
        w[i] = fmaf(bcoef, pw[i], c * w[i]);
    }
    if (any == 0ULL) break;
  }

  // --- lambda = ||w|| - mu; ranks; Eorb; v = w * (occ/||w||) ---
  float a2 = 0.f;
  #pragma unroll
  for (int i = 0; i < 64; ++i) a2 = fmaf(w[i], w[i], a2);
  float lamS = sqrtf(a2);
  float lam  = lamS - mu;
  int rank = 0;
  for (int k = 0; k < 64; ++k){
    float lk = __shfl(lam, k);
    rank += (lk < lam || (lk == lam && k < lane)) ? 1 : 0;
  }
  out[(size_t)mol*65 + 1 + rank] = lam;

  float occf = (rank < 32) ? 1.f : 0.f;
  float slam = occf * lam;
  #pragma unroll
  for (int d = 1; d < 64; d <<= 1) slam += __shfl_xor(slam, d);

  float scale = occf / lamS;
  #pragma unroll
  for (int i = 0; i < 64; ++i) w[i] *= scale;   // w := v_occ column

  // --- O = X * V_occ (X still staged in LDS) ---
  float o[64];
  #pragma unroll
  for (int i = 0; i < 64; ++i){
    float acc = 0.f;
    #pragma unroll
    for (int k = 0; k < 64; k += 4){
      float4 xv = *reinterpret_cast<const float4*>(&B[i*68 + k]);
      acc = fmaf(xv.x, w[k], acc);   acc = fmaf(xv.y, w[k+1], acc);
      acc = fmaf(xv.z, w[k+2], acc); acc = fmaf(xv.w, w[k+3], acc);
    }
    o[i] = acc;
  }
  // --- U = S * O  (S rows broadcast from global; L2-resident) ---
  float u2[64];
  #pragma unroll
  for (int i = 0; i < 64; ++i){
    float acc = 0.f;
    #pragma unroll
    for (int k = 0; k < 64; k += 4){
      float4 sv = *reinterpret_cast<const float4*>(Sm + i*64 + k);
      acc = fmaf(sv.x, o[k], acc);   acc = fmaf(sv.y, o[k+1], acc);
      acc = fmaf(sv.z, o[k+2], acc); acc = fmaf(sv.w, o[k+3], acc);
    }
    u2[i] = acc;
  }
  // --- ener1 = 2*sum(lam_occ) + 2*sum_ik ep_i O_ik U_ik ---
  float term = 0.f;
  #pragma unroll
  for (int i = 0; i < 64; ++i) term = fmaf(__shfl(epl, i), o[i]*u2[i], term);
  #pragma unroll
  for (int d = 1; d < 64; d <<= 1) term += __shfl_xor(term, d);

  if (lane == 0){
    out[(size_t)mol*65] = 2.f*slam + 2.f*term + ener2_a[mol] + erep_a[mol];
  }
}

// ---------------------------------------------------------------------------
extern "C" void kernel_launch(void* const* d_in, const int* in_sizes, int n_in,
                              void* d_out, int out_size, void* d_ws, size_t ws_size,
                              hipStream_t stream){
  (void)in_sizes; (void)n_in; (void)out_size; (void)ws_size;
  const float* A          = (const float*)d_in[0];
  const float* b          = (const float*)d_in[1];
  const float* coeffs     = (const float*)d_in[2];
  const float* rot_tensor = (const float*)d_in[3];
  const float* S          = (const float*)d_in[4];
  const float* G          = (const float*)d_in[5];
  const float* rho        = (const float*)d_in[6];
  const float* qneutral   = (const float*)d_in[7];
  const int* g_rot_direct = (const int*)d_in[9];
  const int* g_rot        = (const int*)d_in[10];
  const int* g_oper       = (const int*)d_in[11];
  const int* g_rep        = (const int*)d_in[12];
  const int* seg_ids      = (const int*)d_in[13];
  float* out = (float*)d_out;

  float* W       = (float*)d_ws;
  float* net     = W;                    // 500000
  float* rot_out = W + 500000;           // 700002 (padded to 700004)
  float* ep_all  = W + 1200004;          // 2048*64
  float* ener2_a = W + 1331076;          // 2048
  float* erep_a  = W + 1333124;          // 2048
  float* X_all   = W + 1335172;          // 2048*4096

  k_netvals<<<(NSPC*16)/256, 256, 0, stream>>>(A, b, coeffs, net);
  k_rot<<<(L0C + NROTC + 255)/256, 256, 0, stream>>>(net, rot_tensor, g_rot_direct, g_rot, rot_out);
  k_coulomb<<<NMOLC, 256, 0, stream>>>(S, G, rho, qneutral, ep_all, ener2_a, erep_a);
  k_erep<<<((NREPC + 63)/64 + 255)/256, 256, 0, stream>>>(net, g_rep, seg_ids, erep_a);
  k_ns<<<NMOLC, 256, 0, stream>>>(S, X_all);
  k_jac<<<NMOLC, 64, 0, stream>>>(S, X_all, g_oper, rot_out, ep_all, ener2_a, erep_a, out);
}

// Round 10
// 694.044 us; speedup vs baseline: 2.2604x; 1.2726x over previous
//
#include <hip/hip_runtime.h>

// ---------------------------------------------------------------------------
// DFTB layer, round 10.
//  K1 netvals / K2 rot / K3 coulomb / K4 erep  (unchanged)
//  K5 k_ns  : Newton-Schulz S^{-1/2}, 3 iters = 6 matmuls (validated)
//  K6 k_jac : r9 structure everywhere EXCEPT the Jacobi sweep loop, which is
//             rewritten as split-row XOR-block one-sided Jacobi:
//              - processor p = lanes (p, p+32); lane holds 32 rows of cols A,B
//              - rotation is lane-local (no partner fetch at all)
//              - only B migrates: 32 shfl_xor/round (vs 64 bpermute in r9)
//              - schedule: masks m = M^e, M = 32..1, e in reflected Gray order
//                (ends at e_last = M/2 so each block transition is a single
//                column exchange with proc p^(M/2)) -- verified on 8-col case
//              - disassemble/reassemble to col-per-lane at sweep boundaries
// ---------------------------------------------------------------------------

#define NMOLC 2048
#define NSPC  500000
#define L0C   100000
#define NROTC 200000
#define NREPC 500000
#define MS 68   // LDS row stride for k_ns matmul buffers

// ---------------- K1: net_vals = A @ coeffs + b ----------------
__global__ __launch_bounds__(256) void k_netvals(const float* __restrict__ A,
                                                 const float* __restrict__ b,
                                                 const float* __restrict__ coeffs,
                                                 float* __restrict__ net){
  int gid = blockIdx.x * 256 + threadIdx.x;
  int row = gid >> 4;
  int l   = gid & 15;
  if (row >= NSPC) return;
  float4 c4 = reinterpret_cast<const float4*>(coeffs)[l];
  float4 a4 = reinterpret_cast<const float4*>(A)[(size_t)row * 16 + l];
  float s = a4.x*c4.x + a4.y*c4.y + a4.z*c4.z + a4.w*c4.w;
  s += __shfl_xor(s, 1, 16);
  s += __shfl_xor(s, 2, 16);
  s += __shfl_xor(s, 4, 16);
  s += __shfl_xor(s, 8, 16);
  if (l == 0) net[row] = s + b[row];
}

// ---------------- K2: rot_out = [0,1] ++ direct ++ rotated ----------------
__global__ __launch_bounds__(256) void k_rot(const float* __restrict__ net,
                                             const float* __restrict__ rot_tensor,
                                             const int* __restrict__ g_rot_direct,
                                             const int* __restrict__ g_rot,
                                             float* __restrict__ rot_out){
  int gid = blockIdx.x * 256 + threadIdx.x;
  if (gid == 0){ rot_out[0] = 0.f; rot_out[1] = 1.f; }
  if (gid < L0C){
    rot_out[2 + gid] = net[g_rot_direct[gid]];
  }
  int n = gid - L0C;
  if (n >= 0 && n < NROTC){
    float v0 = net[g_rot[3*n    ]];
    float v1 = net[g_rot[3*n + 1]];
    float v2 = net[g_rot[3*n + 2]];
    const float* R = rot_tensor + (size_t)9 * n;
    float* o = rot_out + 2 + L0C + 3*n;
    o[0] = R[0]*v0 + R[1]*v1 + R[2]*v2;
    o[1] = R[3]*v0 + R[4]*v1 + R[5]*v2;
    o[2] = R[6]*v0 + R[7]*v1 + R[8]*v2;
  }
}

// ---------------- K3: dQ, ep = G@dQ, ener2; zero erep ----------------
__global__ __launch_bounds__(256) void k_coulomb(const float* __restrict__ S,
                                                 const float* __restrict__ G,
                                                 const float* __restrict__ rho,
                                                 const float* __restrict__ qneutral,
                                                 float* __restrict__ ep_all,
                                                 float* __restrict__ ener2_a,
                                                 float* __restrict__ erep_a){
  __shared__ float sRed[256];
  __shared__ float sdQ[64];
  __shared__ float sEp[64];
  const int mol = blockIdx.x;
  const int t = threadIdx.x;
  const int i = t >> 2, q4 = t & 3;
  const float* Sm = S   + (size_t)mol * 4096;
  const float* Gm = G   + (size_t)mol * 4096;
  const float* Rm = rho + (size_t)mol * 4096;

  float acc = 0.f;
  {
    const float4* S4 = reinterpret_cast<const float4*>(Sm + i*64 + q4*16);
    const float4* R4 = reinterpret_cast<const float4*>(Rm + i*64 + q4*16);
    #pragma unroll
    for (int m = 0; m < 4; ++m){
      float4 sv = S4[m], rv = R4[m];
      acc += sv.x*rv.x + sv.y*rv.y + sv.z*rv.z + sv.w*rv.w;
    }
  }
  sRed[t] = acc; __syncthreads();
  if (t < 64) sdQ[t] = qneutral[(size_t)mol*64 + t]
                       - (sRed[4*t] + sRed[4*t+1] + sRed[4*t+2] + sRed[4*t+3]);
  __syncthreads();

  float acc2 = 0.f;
  {
    const float4* G4 = reinterpret_cast<const float4*>(Gm + i*64 + q4*16);
    #pragma unroll
    for (int m = 0; m < 4; ++m){
      float4 gv = G4[m];
      int j0 = q4*16 + m*4;
      acc2 += gv.x*sdQ[j0] + gv.y*sdQ[j0+1] + gv.z*sdQ[j0+2] + gv.w*sdQ[j0+3];
    }
  }
  sRed[t] = acc2; __syncthreads();
  if (t < 64){
    float e = sRed[4*t] + sRed[4*t+1] + sRed[4*t+2] + sRed[4*t+3];
    sEp[t] = e;
    ep_all[(size_t)mol*64 + t] = e;
  }
  __syncthreads();
  if (t == 0){
    float s = 0.f;
    for (int j = 0; j < 64; ++j) s += sdQ[j] * sEp[j];
    ener2_a[mol] = 0.5f * s;
    erep_a[mol]  = 0.f;
  }
}

// ---------------- K4: Erep segment sum (sorted seg ids) ----------------
__global__ __launch_bounds__(256) void k_erep(const float* __restrict__ net,
                                              const int* __restrict__ g_rep,
                                              const int* __restrict__ seg_ids,
                                              float* __restrict__ erep_a){
  const int CH = 64;
  long tid = (long)blockIdx.x * 256 + threadIdx.x;
  long start = tid * CH;
  if (start >= NREPC) return;
  long end = start + CH; if (end > NREPC) end = NREPC;
  int cur = seg_ids[start];
  float acc = 0.f;
  for (long e = start; e < end; ++e){
    int sgid = seg_ids[e];
    if (sgid != cur){ atomicAdd(&erep_a[cur], acc); cur = sgid; acc = 0.f; }
    acc += net[g_rep[e]];
  }
  atomicAdd(&erep_a[cur], acc);
}

// ---------------- LDS matmul helper (64x64, stride MS), A symmetric ------
__device__ __forceinline__ void mm_symA(float (*__restrict__ D)[MS],
                                        const float (*__restrict__ A)[MS],
                                        const float (*__restrict__ B)[MS],
                                        float alpha, float diag, int t){
  const int r0 = (t & 15) << 2, c0 = (t >> 4) << 2;
  float acc[4][4];
  #pragma unroll
  for (int i = 0; i < 4; ++i)
    #pragma unroll
    for (int j = 0; j < 4; ++j) acc[i][j] = 0.f;
  #pragma unroll 8
  for (int k = 0; k < 64; ++k){
    float4 av = *reinterpret_cast<const float4*>(&A[k][r0]);
    float4 bv = *reinterpret_cast<const float4*>(&B[k][c0]);
    float a_[4] = {av.x, av.y, av.z, av.w};
    float b_[4] = {bv.x, bv.y, bv.z, bv.w};
    #pragma unroll
    for (int i = 0; i < 4; ++i)
      #pragma unroll
      for (int j = 0; j < 4; ++j)
        acc[i][j] += a_[i] * b_[j];
  }
  #pragma unroll
  for (int i = 0; i < 4; ++i)
    #pragma unroll
    for (int j = 0; j < 4; ++j)
      D[r0+i][c0+j] = alpha * acc[i][j] + ((r0+i) == (c0+j) ? diag : 0.f);
}

// ---------------- K5: Newton-Schulz -> X = S^{-1/2} (3 iters, 6 mm) ------
__global__ __launch_bounds__(256, 2) void k_ns(const float* __restrict__ S,
                                               float* __restrict__ X_all){
  __shared__ float M[4][64][MS];
  const int t   = threadIdx.x;
  const int mol = blockIdx.x;
  const float* Sm = S + (size_t)mol * 4096;

  // init: M0 = S, M2 = 3I - S
  #pragma unroll
  for (int m = 0; m < 16; ++m){
    int e = t + (m << 8);
    int i = e >> 6, j = e & 63;
    float s = Sm[e];
    M[0][i][j] = s;
    M[2][i][j] = ((i == j) ? 3.f : 0.f) - s;
  }
  __syncthreads();
  mm_symA(M[3], M[0], M[2], 0.5f, 0.f, t);          // Y1 = 0.5 S (3I-S)
  #pragma unroll
  for (int m = 0; m < 16; ++m){
    int e = t + (m << 8);
    M[1][e >> 6][e & 63] = 0.5f * M[2][e >> 6][e & 63];  // Z1 = 0.5(3I-S)
  }
  __syncthreads();
  // iter2: Y=M3, Z=M1
  mm_symA(M[0], M[1], M[3], -1.f, 3.f, t); __syncthreads();  // T2 = 3I - Z1*Y1
  mm_symA(M[2], M[3], M[0], 0.5f, 0.f, t); __syncthreads();  // Y2 = 0.5*Y1*T2
  mm_symA(M[3], M[0], M[1], 0.5f, 0.f, t); __syncthreads();  // Z2 = 0.5*T2*Z1
  // iter3 (Z-only): Y=M2, Z=M3
  mm_symA(M[1], M[3], M[2], -1.f, 3.f, t); __syncthreads();  // T3 = 3I - Z2*Y2
  mm_symA(M[0], M[1], M[3], 0.5f, 0.f, t); __syncthreads();  // X  = 0.5*T3*Z2

  #pragma unroll
  for (int m = 0; m < 16; ++m){
    int e = t + (m << 8);
    X_all[(size_t)mol * 4096 + e] = M[0][e >> 6][e & 63];
  }
}

// ---------------- K6: one-wave fockp + split-row XOR-block Jacobi --------
__global__ __launch_bounds__(64, 2) void k_jac(const float* __restrict__ S,
                                               const float* __restrict__ X_all,
                                               const int* __restrict__ g_oper,
                                               const float* __restrict__ rot_out,
                                               const float* __restrict__ ep_all,
                                               const float* __restrict__ ener2_a,
                                               const float* __restrict__ erep_a,
                                               float* __restrict__ out){
  __shared__ float B[64 * 68];          // one staging buffer, reused
  const int lane = threadIdx.x;
  const int mol  = blockIdx.x;
  const float* Xm = X_all + (size_t)mol * 4096;
  const float* Sm = S     + (size_t)mol * 4096;
  const int*   gm = g_oper + (size_t)mol * 4096;
  const float  epl = ep_all[(size_t)mol*64 + lane];

  // --- H gather (stride 65: transpose read is 2-way -> free) ---
  float h[64];
  #pragma unroll
  for (int i = 0; i < 64; ++i){
    float v = rot_out[gm[i*64 + lane]];
    h[i] = v;
    B[i*65 + lane] = v;
  }
  __syncthreads();
  // F column: f[i] = 0.5(H_ij + H_ji) - 0.5 S_ij (ep_i + ep_j)
  #pragma unroll
  for (int i = 0; i < 64; ++i){
    float hji = B[lane*65 + i];
    float epi = __shfl(epl, i);
    h[i] = 0.5f*(h[i] + hji) - 0.5f*Sm[i*64 + lane]*(epi + epl);
  }
  __syncthreads();
  // stage F (stride 68, float4-aligned rows for broadcast b128 reads)
  #pragma unroll
  for (int i = 0; i < 64; ++i) B[i*68 + lane] = h[i];
  __syncthreads();

  // --- T = F*X: tt[i] = sum_k F[i][k] * x[k], F broadcast from LDS ---
  float x[64];
  #pragma unroll
  for (int i = 0; i < 64; ++i) x[i] = Xm[i*64 + lane];
  float tt[64];
  #pragma unroll
  for (int i = 0; i < 64; ++i){
    float acc = 0.f;
    #pragma unroll
    for (int k = 0; k < 64; k += 4){
      float4 fv = *reinterpret_cast<const float4*>(&B[i*68 + k]);
      acc = fmaf(fv.x, x[k], acc);   acc = fmaf(fv.y, x[k+1], acc);
      acc = fmaf(fv.z, x[k+2], acc); acc = fmaf(fv.w, x[k+3], acc);
    }
    tt[i] = acc;
  }
  __syncthreads();
  // stage X (kept resident in LDS through Jacobi for the epilogue)
  #pragma unroll
  for (int i = 0; i < 64; ++i) B[i*68 + lane] = x[i];
  __syncthreads();

  // --- w = X*T (fockp column) ---
  float w[64];
  #pragma unroll
  for (int i = 0; i < 64; ++i){
    float acc = 0.f;
    #pragma unroll
    for (int k = 0; k < 64; k += 4){
      float4 xv = *reinterpret_cast<const float4*>(&B[i*68 + k]);
      acc = fmaf(xv.x, tt[k], acc);   acc = fmaf(xv.y, tt[k+1], acc);
      acc = fmaf(xv.z, tt[k+2], acc); acc = fmaf(xv.w, tt[k+3], acc);
    }
    w[i] = acc;
  }

  // --- Gershgorin shift (PD): mu = 1.02 * max col abs-sum ---
  float csum = 0.f;
  #pragma unroll
  for (int i = 0; i < 64; ++i) csum += fabsf(w[i]);
  float mu = csum;
  #pragma unroll
  for (int d = 1; d < 64; d <<= 1) mu = fmaxf(mu, __shfl_xor(mu, d));
  mu *= 1.02f;
  #pragma unroll
  for (int i = 0; i < 64; ++i) w[i] += (i == lane) ? mu : 0.f;

  // --- split-row XOR-block one-sided Jacobi ---
  // processor p = (lane&31) paired across halves (lane, lane+32);
  // lane holds rows [half*32, half*32+32) of columns A and B.
  const int pid  = lane & 31;
  const int half = lane >> 5;
  for (int sweep = 0; sweep < 5; ++sweep){
    // disassemble w (col-per-lane) -> A = col(pid), B = col(32+pid) rows[half]
    float Ac[32], Bc[32];
    #pragma unroll
    for (int i = 0; i < 32; ++i){
      float t0 = __shfl(w[i],      pid);
      float t1 = __shfl(w[i + 32], pid);
      Ac[i] = half ? t1 : t0;
      float u0 = __shfl(w[i],      32 + pid);
      float u1 = __shfl(w[i + 32], 32 + pid);
      Bc[i] = half ? u1 : u0;
    }
    // alpha = ||A||^2, beta = ||B||^2 (exact, cross-half combine)
    float al = 0.f, bl = 0.f;
    #pragma unroll
    for (int i = 0; i < 32; ++i){
      al = fmaf(Ac[i], Ac[i], al);
      bl = fmaf(Bc[i], Bc[i], bl);
    }
    float alpha = al + __shfl_xor(al, 32);
    float beta  = bl + __shfl_xor(bl, 32);

    unsigned long long any = 0ULL;
    // blocks M = 32,16,8,4,2,1: block M covers masks m = M^e, e in Gray order
    for (int j = 5; j >= 0; --j){
      const int M = 1 << j;
      for (int k = 0; k < M; ++k){
        // rotate pair (A,B): A has the lower column index by construction
        float gl = 0.f;
        #pragma unroll
        for (int i = 0; i < 32; ++i) gl = fmaf(Ac[i], Bc[i], gl);
        float gamma = gl + __shfl_xor(gl, 32);
        bool rot = (gamma * gamma) > (1e-9f * alpha * beta);
        unsigned long long bal = __ballot(rot);
        any |= bal;
        if (bal != 0ULL){
          float tau = (beta - alpha) / (2.f * gamma);
          float tq  = copysignf(1.f, tau) / (fabsf(tau) + sqrtf(fmaf(tau, tau, 1.f)));
          float c = rsqrtf(fmaf(tq, tq, 1.f));
          float s = tq * c;
          if (!rot){ c = 1.f; s = 0.f; }
          float na = c*c*alpha + s*s*beta - 2.f*c*s*gamma;
          float nb = s*s*alpha + c*c*beta + 2.f*c*s*gamma;
          alpha = na; beta = nb;
          #pragma unroll
          for (int i = 0; i < 32; ++i){
            float ta = Ac[i];
            Ac[i] = fmaf(-s, Bc[i], c * ta);
            Bc[i] = fmaf( c, Bc[i], s * ta);
          }
        }
        if (k < M - 1){
          // Gray-step migration of B within the block (single-bit xor < 32)
          int e  = k ^ (k >> 1);
          int e2 = (k + 1) ^ ((k + 1) >> 1);
          int mig = e ^ e2;
          #pragma unroll
          for (int i = 0; i < 32; ++i) Bc[i] = __shfl_xor(Bc[i], mig);
          beta = __shfl_xor(beta, mig);
        } else if (j > 0){
          // block transition M -> M/2 (Gray ends at e_last = M/2):
          // exchange one column with proc p^(M/2); local slot swap.
          const int Mp = M >> 1;
          const bool hb = (pid & Mp) != 0;
          #pragma unroll
          for (int i = 0; i < 32; ++i){
            float send = hb ? Ac[i] : Bc[i];
            float recv = __shfl_xor(send, Mp);
            Ac[i] = hb ? Bc[i] : Ac[i];
            Bc[i] = recv;
          }
          float sendb = hb ? alpha : beta;
          float recvb = __shfl_xor(sendb, Mp);
          alpha = hb ? beta : alpha;
          beta  = recvb;
        }
      }
    }
    // reassemble: after block M=1, proc p holds cols (2p, 2p+1) -> lane l = col l
    {
      const int srcq = lane >> 1;
      const int slot = lane & 1;
      #pragma unroll
      for (int i = 0; i < 32; ++i){
        float a0 = __shfl(Ac[i], srcq);
        float b0 = __shfl(Bc[i], srcq);
        w[i] = slot ? b0 : a0;
        float a1 = __shfl(Ac[i], srcq + 32);
        float b1 = __shfl(Bc[i], srcq + 32);
        w[i + 32] = slot ? b1 : a1;
      }
    }
    if (any == 0ULL) break;
  }

  // --- lambda = ||w|| - mu; ranks; Eorb; v = w * (occ/||w||) ---
  float a2 = 0.f;
  #pragma unroll
  for (int i = 0; i < 64; ++i) a2 = fmaf(w[i], w[i], a2);
  float lamS = sqrtf(a2);
  float lam  = lamS - mu;
  int rank = 0;
  for (int k = 0; k < 64; ++k){
    float lk = __shfl(lam, k);
    rank += (lk < lam || (lk == lam && k < lane)) ? 1 : 0;
  }
  out[(size_t)mol*65 + 1 + rank] = lam;

  float occf = (rank < 32) ? 1.f : 0.f;
  float slam = occf * lam;
  #pragma unroll
  for (int d = 1; d < 64; d <<= 1) slam += __shfl_xor(slam, d);

  float scale = occf / lamS;
  #pragma unroll
  for (int i = 0; i < 64; ++i) w[i] *= scale;   // w := v_occ column

  // --- O = X * V_occ (X still staged in LDS) ---
  float o[64];
  #pragma unroll
  for (int i = 0; i < 64; ++i){
    float acc = 0.f;
    #pragma unroll
    for (int k = 0; k < 64; k += 4){
      float4 xv = *reinterpret_cast<const float4*>(&B[i*68 + k]);
      acc = fmaf(xv.x, w[k], acc);   acc = fmaf(xv.y, w[k+1], acc);
      acc = fmaf(xv.z, w[k+2], acc); acc = fmaf(xv.w, w[k+3], acc);
    }
    o[i] = acc;
  }
  // --- U = S * O  (S rows broadcast from global; L2-resident) ---
  float u2[64];
  #pragma unroll
  for (int i = 0; i < 64; ++i){
    float acc = 0.f;
    #pragma unroll
    for (int k = 0; k < 64; k += 4){
      float4 sv = *reinterpret_cast<const float4*>(Sm + i*64 + k);
      acc = fmaf(sv.x, o[k], acc);   acc = fmaf(sv.y, o[k+1], acc);
      acc = fmaf(sv.z, o[k+2], acc); acc = fmaf(sv.w, o[k+3], acc);
    }
    u2[i] = acc;
  }
  // --- ener1 = 2*sum(lam_occ) + 2*sum_ik ep_i O_ik U_ik ---
  float term = 0.f;
  #pragma unroll
  for (int i = 0; i < 64; ++i) term = fmaf(__shfl(epl, i), o[i]*u2[i], term);
  #pragma unroll
  for (int d = 1; d < 64; d <<= 1) term += __shfl_xor(term, d);

  if (lane == 0){
    out[(size_t)mol*65] = 2.f*slam + 2.f*term + ener2_a[mol] + erep_a[mol];
  }
}

// ---------------------------------------------------------------------------
extern "C" void kernel_launch(void* const* d_in, const int* in_sizes, int n_in,
                              void* d_out, int out_size, void* d_ws, size_t ws_size,
                              hipStream_t stream){
  (void)in_sizes; (void)n_in; (void)out_size; (void)ws_size;
  const float* A          = (const float*)d_in[0];
  const float* b          = (const float*)d_in[1];
  const float* coeffs     = (const float*)d_in[2];
  const float* rot_tensor = (const float*)d_in[3];
  const float* S          = (const float*)d_in[4];
  const float* G          = (const float*)d_in[5];
  const float* rho        = (const float*)d_in[6];
  const float* qneutral   = (const float*)d_in[7];
  const int* g_rot_direct = (const int*)d_in[9];
  const int* g_rot        = (const int*)d_in[10];
  const int* g_oper       = (const int*)d_in[11];
  const int* g_rep        = (const int*)d_in[12];
  const int* seg_ids      = (const int*)d_in[13];
  float* out = (float*)d_out;

  float* W       = (float*)d_ws;
  float* net     = W;                    // 500000
  float* rot_out = W + 500000;           // 700002 (padded to 700004)
  float* ep_all  = W + 1200004;          // 2048*64
  float* ener2_a = W + 1331076;          // 2048
  float* erep_a  = W + 1333124;          // 2048
  float* X_all   = W + 1335172;          // 2048*4096

  k_netvals<<<(NSPC*16)/256, 256, 0, stream>>>(A, b, coeffs, net);
  k_rot<<<(L0C + NROTC + 255)/256, 256, 0, stream>>>(net, rot_tensor, g_rot_direct, g_rot, rot_out);
  k_coulomb<<<NMOLC, 256, 0, stream>>>(S, G, rho, qneutral, ep_all, ener2_a, erep_a);
  k_erep<<<((NREPC + 63)/64 + 255)/256, 256, 0, stream>>>(net, g_rep, seg_ids, erep_a);
  k_ns<<<NMOLC, 256, 0, stream>>>(S, X_all);
  k_jac<<<NMOLC, 64, 0, stream>>>(S, X_all, g_oper, rot_out, ep_all, ener2_a, erep_a, out);
}

// Round 11
// 677.334 us; speedup vs baseline: 2.3161x; 1.0247x over previous
//
#include <hip/hip_runtime.h>

// ---------------------------------------------------------------------------
// DFTB layer, round 11.
//  K1 netvals / K2 rot / K3 coulomb / K4 erep  (unchanged)
//  K5 k_ns  : NS S^{-1/2} (6 mm) + fockp = X F X (2 mm) + C2 = X E S X (2 mm)
//             at 256 threads, 2 blocks/CU. k_jac no longer needs X/S/H/ep:
//             term identity  ener1_corr = sum_occ v^T (X diag(ep) S X) v.
//  K6 k_jac : split-row XOR-block Jacobi (r10-measured inner loop, bank-
//             conflict-free). New: direct split-layout load of fockp, NO
//             inter-sweep disassembly/reassembly (schedule is layout-
//             invariant; column identity never needed), 4 sweeps, epilogue
//             reads staged C2 with one 1024-broadcast matvec.
//  ws: net/rot/ep/scalars (5.35MB) + fockp (32MB) + C2 (32MB) ~= 72.5MB.
// ---------------------------------------------------------------------------

#define NMOLC 2048
#define NSPC  500000
#define L0C   100000
#define NROTC 200000
#define NREPC 500000
#define MS 68   // LDS row stride for k_ns matmul buffers

// ---------------- K1: net_vals = A @ coeffs + b ----------------
__global__ __launch_bounds__(256) void k_netvals(const float* __restrict__ A,
                                                 const float* __restrict__ b,
                                                 const float* __restrict__ coeffs,
                                                 float* __restrict__ net){
  int gid = blockIdx.x * 256 + threadIdx.x;
  int row = gid >> 4;
  int l   = gid & 15;
  if (row >= NSPC) return;
  float4 c4 = reinterpret_cast<const float4*>(coeffs)[l];
  float4 a4 = reinterpret_cast<const float4*>(A)[(size_t)row * 16 + l];
  float s = a4.x*c4.x + a4.y*c4.y + a4.z*c4.z + a4.w*c4.w;
  s += __shfl_xor(s, 1, 16);
  s += __shfl_xor(s, 2, 16);
  s += __shfl_xor(s, 4, 16);
  s += __shfl_xor(s, 8, 16);
  if (l == 0) net[row] = s + b[row];
}

// ---------------- K2: rot_out = [0,1] ++ direct ++ rotated ----------------
__global__ __launch_bounds__(256) void k_rot(const float* __restrict__ net,
                                             const float* __restrict__ rot_tensor,
                                             const int* __restrict__ g_rot_direct,
                                             const int* __restrict__ g_rot,
                                             float* __restrict__ rot_out){
  int gid = blockIdx.x * 256 + threadIdx.x;
  if (gid == 0){ rot_out[0] = 0.f; rot_out[1] = 1.f; }
  if (gid < L0C){
    rot_out[2 + gid] = net[g_rot_direct[gid]];
  }
  int n = gid - L0C;
  if (n >= 0 && n < NROTC){
    float v0 = net[g_rot[3*n    ]];
    float v1 = net[g_rot[3*n + 1]];
    float v2 = net[g_rot[3*n + 2]];
    const float* R = rot_tensor + (size_t)9 * n;
    float* o = rot_out + 2 + L0C + 3*n;
    o[0] = R[0]*v0 + R[1]*v1 + R[2]*v2;
    o[1] = R[3]*v0 + R[4]*v1 + R[5]*v2;
    o[2] = R[6]*v0 + R[7]*v1 + R[8]*v2;
  }
}

// ---------------- K3: dQ, ep = G@dQ, ener2; zero erep ----------------
__global__ __launch_bounds__(256) void k_coulomb(const float* __restrict__ S,
                                                 const float* __restrict__ G,
                                                 const float* __restrict__ rho,
                                                 const float* __restrict__ qneutral,
                                                 float* __restrict__ ep_all,
                                                 float* __restrict__ ener2_a,
                                                 float* __restrict__ erep_a){
  __shared__ float sRed[256];
  __shared__ float sdQ[64];
  __shared__ float sEp[64];
  const int mol = blockIdx.x;
  const int t = threadIdx.x;
  const int i = t >> 2, q4 = t & 3;
  const float* Sm = S   + (size_t)mol * 4096;
  const float* Gm = G   + (size_t)mol * 4096;
  const float* Rm = rho + (size_t)mol * 4096;

  float acc = 0.f;
  {
    const float4* S4 = reinterpret_cast<const float4*>(Sm + i*64 + q4*16);
    const float4* R4 = reinterpret_cast<const float4*>(Rm + i*64 + q4*16);
    #pragma unroll
    for (int m = 0; m < 4; ++m){
      float4 sv = S4[m], rv = R4[m];
      acc += sv.x*rv.x + sv.y*rv.y + sv.z*rv.z + sv.w*rv.w;
    }
  }
  sRed[t] = acc; __syncthreads();
  if (t < 64) sdQ[t] = qneutral[(size_t)mol*64 + t]
                       - (sRed[4*t] + sRed[4*t+1] + sRed[4*t+2] + sRed[4*t+3]);
  __syncthreads();

  float acc2 = 0.f;
  {
    const float4* G4 = reinterpret_cast<const float4*>(Gm + i*64 + q4*16);
    #pragma unroll
    for (int m = 0; m < 4; ++m){
      float4 gv = G4[m];
      int j0 = q4*16 + m*4;
      acc2 += gv.x*sdQ[j0] + gv.y*sdQ[j0+1] + gv.z*sdQ[j0+2] + gv.w*sdQ[j0+3];
    }
  }
  sRed[t] = acc2; __syncthreads();
  if (t < 64){
    float e = sRed[4*t] + sRed[4*t+1] + sRed[4*t+2] + sRed[4*t+3];
    sEp[t] = e;
    ep_all[(size_t)mol*64 + t] = e;
  }
  __syncthreads();
  if (t == 0){
    float s = 0.f;
    for (int j = 0; j < 64; ++j) s += sdQ[j] * sEp[j];
    ener2_a[mol] = 0.5f * s;
    erep_a[mol]  = 0.f;
  }
}

// ---------------- K4: Erep segment sum (sorted seg ids) ----------------
__global__ __launch_bounds__(256) void k_erep(const float* __restrict__ net,
                                              const int* __restrict__ g_rep,
                                              const int* __restrict__ seg_ids,
                                              float* __restrict__ erep_a){
  const int CH = 64;
  long tid = (long)blockIdx.x * 256 + threadIdx.x;
  long start = tid * CH;
  if (start >= NREPC) return;
  long end = start + CH; if (end > NREPC) end = NREPC;
  int cur = seg_ids[start];
  float acc = 0.f;
  for (long e = start; e < end; ++e){
    int sgid = seg_ids[e];
    if (sgid != cur){ atomicAdd(&erep_a[cur], acc); cur = sgid; acc = 0.f; }
    acc += net[g_rep[e]];
  }
  atomicAdd(&erep_a[cur], acc);
}

// ---------------- LDS matmul helper (64x64, stride MS), A symmetric ------
__device__ __forceinline__ void mm_symA(float (*__restrict__ D)[MS],
                                        const float (*__restrict__ A)[MS],
                                        const float (*__restrict__ B)[MS],
                                        float alpha, float diag, int t){
  const int r0 = (t & 15) << 2, c0 = (t >> 4) << 2;
  float acc[4][4];
  #pragma unroll
  for (int i = 0; i < 4; ++i)
    #pragma unroll
    for (int j = 0; j < 4; ++j) acc[i][j] = 0.f;
  #pragma unroll 8
  for (int k = 0; k < 64; ++k){
    float4 av = *reinterpret_cast<const float4*>(&A[k][r0]);
    float4 bv = *reinterpret_cast<const float4*>(&B[k][c0]);
    float a_[4] = {av.x, av.y, av.z, av.w};
    float b_[4] = {bv.x, bv.y, bv.z, bv.w};
    #pragma unroll
    for (int i = 0; i < 4; ++i)
      #pragma unroll
      for (int j = 0; j < 4; ++j)
        acc[i][j] += a_[i] * b_[j];
  }
  #pragma unroll
  for (int i = 0; i < 4; ++i)
    #pragma unroll
    for (int j = 0; j < 4; ++j)
      D[r0+i][c0+j] = alpha * acc[i][j] + ((r0+i) == (c0+j) ? diag : 0.f);
}

// ---- K5: NS X=S^{-1/2} (6 mm) + fockp = X F X + C2 = X E S X (4 mm) -----
__global__ __launch_bounds__(256, 2) void k_ns(const float* __restrict__ S,
                                               const int* __restrict__ g_oper,
                                               const float* __restrict__ rot_out,
                                               const float* __restrict__ ep_all,
                                               float* __restrict__ fockp_all,
                                               float* __restrict__ C2_all){
  __shared__ float M[4][64][MS];
  __shared__ float sEp[64];
  const int t   = threadIdx.x;
  const int mol = blockIdx.x;
  const float* Sm = S + (size_t)mol * 4096;
  const int*   gm = g_oper + (size_t)mol * 4096;

  // init: M0 = S, M2 = 3I - S
  #pragma unroll
  for (int m = 0; m < 16; ++m){
    int e = t + (m << 8);
    int i = e >> 6, j = e & 63;
    float s = Sm[e];
    M[0][i][j] = s;
    M[2][i][j] = ((i == j) ? 3.f : 0.f) - s;
  }
  if (t < 64) sEp[t] = ep_all[(size_t)mol*64 + t];
  __syncthreads();
  mm_symA(M[3], M[0], M[2], 0.5f, 0.f, t);          // Y1 = 0.5 S (3I-S)
  #pragma unroll
  for (int m = 0; m < 16; ++m){
    int e = t + (m << 8);
    M[1][e >> 6][e & 63] = 0.5f * M[2][e >> 6][e & 63];  // Z1 = 0.5(3I-S)
  }
  __syncthreads();
  // iter2: Y=M3, Z=M1
  mm_symA(M[0], M[1], M[3], -1.f, 3.f, t); __syncthreads();  // T2 = 3I - Z1*Y1
  mm_symA(M[2], M[3], M[0], 0.5f, 0.f, t); __syncthreads();  // Y2 = 0.5*Y1*T2
  mm_symA(M[3], M[0], M[1], 0.5f, 0.f, t); __syncthreads();  // Z2 = 0.5*T2*Z1
  // iter3 (Z-only): Y=M2, Z=M3
  mm_symA(M[1], M[3], M[2], -1.f, 3.f, t); __syncthreads();  // T3 = 3I - Z2*Y2
  mm_symA(M[0], M[1], M[3], 0.5f, 0.f, t); __syncthreads();  // X  = 0.5*T3*Z2
  // buffers now: M0 = X; M1..M3 free

  // --- H gather -> M1 ---
  #pragma unroll
  for (int m = 0; m < 16; ++m){
    int e = t + (m << 8);
    M[1][e >> 6][e & 63] = rot_out[gm[e]];
  }
  __syncthreads();
  // --- F -> M2: F_ij = 0.5(H_ij + H_ji) - 0.5 S_ij (ep_i + ep_j) ---
  #pragma unroll
  for (int m = 0; m < 16; ++m){
    int e = t + (m << 8);
    int i = e >> 6, j = e & 63;
    M[2][i][j] = 0.5f*(M[1][i][j] + M[1][j][i]) - 0.5f*Sm[e]*(sEp[i] + sEp[j]);
  }
  __syncthreads();
  mm_symA(M[3], M[2], M[0], 1.f, 0.f, t); __syncthreads();  // P1 = F*X
  mm_symA(M[1], M[0], M[3], 1.f, 0.f, t); __syncthreads();  // fockp = X*P1
  #pragma unroll
  for (int m = 0; m < 16; ++m){
    int e = t + (m << 8);
    fockp_all[(size_t)mol * 4096 + e] = M[1][e >> 6][e & 63];
  }
  // --- reload S -> M2 ---
  #pragma unroll
  for (int m = 0; m < 16; ++m){
    int e = t + (m << 8);
    M[2][e >> 6][e & 63] = Sm[e];
  }
  __syncthreads();
  mm_symA(M[3], M[2], M[0], 1.f, 0.f, t); __syncthreads();  // C1 = S*X
  // EC1 in place: row-scale by ep
  #pragma unroll
  for (int m = 0; m < 16; ++m){
    int e = t + (m << 8);
    int i = e >> 6, j = e & 63;
    M[3][i][j] *= sEp[i];
  }
  __syncthreads();
  mm_symA(M[1], M[0], M[3], 1.f, 0.f, t); __syncthreads();  // C2 = X*(E C1)
  #pragma unroll
  for (int m = 0; m < 16; ++m){
    int e = t + (m << 8);
    C2_all[(size_t)mol * 4096 + e] = M[1][e >> 6][e & 63];
  }
}

// ---------------- K6: split-row XOR-block Jacobi + energy -----------------
__global__ __launch_bounds__(64, 2) void k_jac(const float* __restrict__ fockp_all,
                                               const float* __restrict__ C2_all,
                                               const float* __restrict__ ener2_a,
                                               const float* __restrict__ erep_a,
                                               float* __restrict__ out){
  __shared__ float B[64 * 68];          // C2 staging for epilogue matvec
  const int lane = threadIdx.x;
  const int mol  = blockIdx.x;
  const float* Am = fockp_all + (size_t)mol * 4096;
  const float* Cm = C2_all    + (size_t)mol * 4096;
  const int pid  = lane & 31;
  const int half = lane >> 5;

  // --- direct split-layout load: proc pid = lanes (pid, pid+32);
  //     lane holds rows [half*32, half*32+32) of cols A=pid, B=32+pid ---
  float Ac[32], Bc[32];
  float csA = 0.f, csB = 0.f;
  #pragma unroll
  for (int i = 0; i < 32; ++i){
    float a = Am[(half*32 + i)*64 + pid];
    float b = Am[(half*32 + i)*64 + 32 + pid];
    Ac[i] = a; Bc[i] = b;
    csA += fabsf(a); csB += fabsf(b);
  }
  // --- Gershgorin shift: mu = 1.02 * max col abs-sum; add to diagonals ---
  csA += __shfl_xor(csA, 32);
  csB += __shfl_xor(csB, 32);
  float mu = fmaxf(csA, csB);
  #pragma unroll
  for (int d = 1; d < 32; d <<= 1) mu = fmaxf(mu, __shfl_xor(mu, d));
  mu *= 1.02f;
  // col A=pid: diag row pid (in half 0); col B=32+pid: diag row 32+pid (half 1)
  #pragma unroll
  for (int i = 0; i < 32; ++i){
    Ac[i] += (half == 0 && i == pid) ? mu : 0.f;
    Bc[i] += (half == 1 && i == pid) ? mu : 0.f;
  }

  // --- XOR-block one-sided Jacobi; NO inter-sweep reassembly (schedule is
  //     layout-invariant; column identity never needed downstream) ---
  for (int sweep = 0; sweep < 4; ++sweep){
    float al = 0.f, bl = 0.f;
    #pragma unroll
    for (int i = 0; i < 32; ++i){
      al = fmaf(Ac[i], Ac[i], al);
      bl = fmaf(Bc[i], Bc[i], bl);
    }
    float alpha = al + __shfl_xor(al, 32);
    float beta  = bl + __shfl_xor(bl, 32);

    unsigned long long any = 0ULL;
    for (int j = 5; j >= 0; --j){
      const int M = 1 << j;
      for (int k = 0; k < M; ++k){
        float gl = 0.f;
        #pragma unroll
        for (int i = 0; i < 32; ++i) gl = fmaf(Ac[i], Bc[i], gl);
        float gamma = gl + __shfl_xor(gl, 32);
        bool rot = (gamma * gamma) > (1e-9f * alpha * beta);
        unsigned long long bal = __ballot(rot);
        any |= bal;
        if (bal != 0ULL){
          float tau = (beta - alpha) / (2.f * gamma);
          float tq  = copysignf(1.f, tau) / (fabsf(tau) + sqrtf(fmaf(tau, tau, 1.f)));
          float c = rsqrtf(fmaf(tq, tq, 1.f));
          float s = tq * c;
          if (!rot){ c = 1.f; s = 0.f; }
          float na = c*c*alpha + s*s*beta - 2.f*c*s*gamma;
          float nb = s*s*alpha + c*c*beta + 2.f*c*s*gamma;
          alpha = na; beta = nb;
          #pragma unroll
          for (int i = 0; i < 32; ++i){
            float ta = Ac[i];
            Ac[i] = fmaf(-s, Bc[i], c * ta);
            Bc[i] = fmaf( c, Bc[i], s * ta);
          }
        }
        if (k < M - 1){
          int e  = k ^ (k >> 1);
          int e2 = (k + 1) ^ ((k + 1) >> 1);
          int mig = e ^ e2;
          #pragma unroll
          for (int i = 0; i < 32; ++i) Bc[i] = __shfl_xor(Bc[i], mig);
          beta = __shfl_xor(beta, mig);
        } else if (j > 0){
          const int Mp = M >> 1;
          const bool hb = (pid & Mp) != 0;
          #pragma unroll
          for (int i = 0; i < 32; ++i){
            float send = hb ? Ac[i] : Bc[i];
            float recv = __shfl_xor(send, Mp);
            Ac[i] = hb ? Bc[i] : Ac[i];
            Bc[i] = recv;
          }
          float sendb = hb ? alpha : beta;
          float recvb = __shfl_xor(sendb, Mp);
          alpha = hb ? beta : alpha;
          beta  = recvb;
        }
      }
    }
    if (any == 0ULL) break;
  }

  // --- final reassemble to one column per lane (any unique assignment ok) ---
  float w[64];
  {
    const int srcq = lane >> 1;
    const int slot = lane & 1;
    #pragma unroll
    for (int i = 0; i < 32; ++i){
      float a0 = __shfl(Ac[i], srcq);
      float b0 = __shfl(Bc[i], srcq);
      w[i] = slot ? b0 : a0;
      float a1 = __shfl(Ac[i], srcq + 32);
      float b1 = __shfl(Bc[i], srcq + 32);
      w[i + 32] = slot ? b1 : a1;
    }
  }

  // --- lambda = ||w|| - mu; ranks; Eorb; v = w * (occ/||w||) ---
  float a2 = 0.f;
  #pragma unroll
  for (int i = 0; i < 64; ++i) a2 = fmaf(w[i], w[i], a2);
  float lamS = sqrtf(a2);
  float lam  = lamS - mu;
  int rank = 0;
  for (int k = 0; k < 64; ++k){
    float lk = __shfl(lam, k);
    rank += (lk < lam || (lk == lam && k < lane)) ? 1 : 0;
  }
  out[(size_t)mol*65 + 1 + rank] = lam;

  float occf = (rank < 32) ? 1.f : 0.f;
  float slam = occf * lam;
  #pragma unroll
  for (int d = 1; d < 64; d <<= 1) slam += __shfl_xor(slam, d);

  float scale = occf / lamS;
  #pragma unroll
  for (int i = 0; i < 64; ++i) w[i] *= scale;   // w := v_occ column (0 if virt)

  // --- stage C2, then term = sum_occ v^T C2 v (per-lane column) ---
  #pragma unroll
  for (int i = 0; i < 64; ++i) B[i*68 + lane] = Cm[i*64 + lane];
  __syncthreads();
  float term = 0.f;
  #pragma unroll 8
  for (int i = 0; i < 64; ++i){
    float dot = 0.f;
    #pragma unroll
    for (int k = 0; k < 64; k += 4){
      float4 cv = *reinterpret_cast<const float4*>(&B[i*68 + k]);
      dot = fmaf(cv.x, w[k], dot);   dot = fmaf(cv.y, w[k+1], dot);
      dot = fmaf(cv.z, w[k+2], dot); dot = fmaf(cv.w, w[k+3], dot);
    }
    term = fmaf(w[i], dot, term);
  }
  #pragma unroll
  for (int d = 1; d < 64; d <<= 1) term += __shfl_xor(term, d);

  if (lane == 0){
    out[(size_t)mol*65] = 2.f*slam + 2.f*term + ener2_a[mol] + erep_a[mol];
  }
}

// ---------------------------------------------------------------------------
extern "C" void kernel_launch(void* const* d_in, const int* in_sizes, int n_in,
                              void* d_out, int out_size, void* d_ws, size_t ws_size,
                              hipStream_t stream){
  (void)in_sizes; (void)n_in; (void)out_size; (void)ws_size;
  const float* A          = (const float*)d_in[0];
  const float* b          = (const float*)d_in[1];
  const float* coeffs     = (const float*)d_in[2];
  const float* rot_tensor = (const float*)d_in[3];
  const float* S          = (const float*)d_in[4];
  const float* G          = (const float*)d_in[5];
  const float* rho        = (const float*)d_in[6];
  const float* qneutral   = (const float*)d_in[7];
  const int* g_rot_direct = (const int*)d_in[9];
  const int* g_rot        = (const int*)d_in[10];
  const int* g_oper       = (const int*)d_in[11];
  const int* g_rep        = (const int*)d_in[12];
  const int* seg_ids      = (const int*)d_in[13];
  float* out = (float*)d_out;

  // ws layout (floats): 5.35MB scalars + fockp 32MB + C2 32MB ~= 72.5MB
  float* W         = (float*)d_ws;
  float* net       = W;                    // 500000
  float* rot_out   = W + 500000;           // 700002 (padded to 700004)
  float* ep_all    = W + 1200004;          // 2048*64
  float* ener2_a   = W + 1331076;          // 2048
  float* erep_a    = W + 1333124;          // 2048
  float* fockp_all = W + 1335172;          // 2048*4096
  float* C2_all    = W + 9723780;          // 2048*4096 (ends 18112388)

  k_netvals<<<(NSPC*16)/256, 256, 0, stream>>>(A, b, coeffs, net);
  k_rot<<<(L0C + NROTC + 255)/256, 256, 0, stream>>>(net, rot_tensor, g_rot_direct, g_rot, rot_out);
  k_coulomb<<<NMOLC, 256, 0, stream>>>(S, G, rho, qneutral, ep_all, ener2_a, erep_a);
  k_erep<<<((NREPC + 63)/64 + 255)/256, 256, 0, stream>>>(net, g_rep, seg_ids, erep_a);
  k_ns<<<NMOLC, 256, 0, stream>>>(S, g_oper, rot_out, ep_all, fockp_all, C2_all);
  k_jac<<<NMOLC, 64, 0, stream>>>(fockp_all, C2_all, ener2_a, erep_a, out);
}

// Round 12
// 582.626 us; speedup vs baseline: 2.6926x; 1.1626x over previous
//
#include <hip/hip_runtime.h>

// ---------------------------------------------------------------------------
// DFTB layer, round 12.
//  K1 netvals / K2 rot / K3 coulomb / K4 erep  (unchanged)
//  K5 k_ns  : NS S^{-1/2} (6 mm) + fockp = X F X + C2 = X E S X (4 mm)
//  K6 k_jac : split-row XOR-block Jacobi (r10/r11-measured inner loop).
//             NEW epilogue fully in split layout -- NO w[64] reassembly
//             (r11 spilled it: 50MB scratch writes + 4096 scratch reads/lane
//             in the C2 matvec). lambda/rank from column norms; quadratic
//             form computed on split columns with one 32-shfl partner fetch
//             per column. C2 staged into LDS BEFORE the sweeps (latency
//             hidden under Jacobi compute).
// ---------------------------------------------------------------------------

#define NMOLC 2048
#define NSPC  500000
#define L0C   100000
#define NROTC 200000
#define NREPC 500000
#define MS 68   // LDS row stride for k_ns matmul buffers

// ---------------- K1: net_vals = A @ coeffs + b ----------------
__global__ __launch_bounds__(256) void k_netvals(const float* __restrict__ A,
                                                 const float* __restrict__ b,
                                                 const float* __restrict__ coeffs,
                                                 float* __restrict__ net){
  int gid = blockIdx.x * 256 + threadIdx.x;
  int row = gid >> 4;
  int l   = gid & 15;
  if (row >= NSPC) return;
  float4 c4 = reinterpret_cast<const float4*>(coeffs)[l];
  float4 a4 = reinterpret_cast<const float4*>(A)[(size_t)row * 16 + l];
  float s = a4.x*c4.x + a4.y*c4.y + a4.z*c4.z + a4.w*c4.w;
  s += __shfl_xor(s, 1, 16);
  s += __shfl_xor(s, 2, 16);
  s += __shfl_xor(s, 4, 16);
  s += __shfl_xor(s, 8, 16);
  if (l == 0) net[row] = s + b[row];
}

// ---------------- K2: rot_out = [0,1] ++ direct ++ rotated ----------------
__global__ __launch_bounds__(256) void k_rot(const float* __restrict__ net,
                                             const float* __restrict__ rot_tensor,
                                             const int* __restrict__ g_rot_direct,
                                             const int* __restrict__ g_rot,
                                             float* __restrict__ rot_out){
  int gid = blockIdx.x * 256 + threadIdx.x;
  if (gid == 0){ rot_out[0] = 0.f; rot_out[1] = 1.f; }
  if (gid < L0C){
    rot_out[2 + gid] = net[g_rot_direct[gid]];
  }
  int n = gid - L0C;
  if (n >= 0 && n < NROTC){
    float v0 = net[g_rot[3*n    ]];
    float v1 = net[g_rot[3*n + 1]];
    float v2 = net[g_rot[3*n + 2]];
    const float* R = rot_tensor + (size_t)9 * n;
    float* o = rot_out + 2 + L0C + 3*n;
    o[0] = R[0]*v0 + R[1]*v1 + R[2]*v2;
    o[1] = R[3]*v0 + R[4]*v1 + R[5]*v2;
    o[2] = R[6]*v0 + R[7]*v1 + R[8]*v2;
  }
}

// ---------------- K3: dQ, ep = G@dQ, ener2; zero erep ----------------
__global__ __launch_bounds__(256) void k_coulomb(const float* __restrict__ S,
                                                 const float* __restrict__ G,
                                                 const float* __restrict__ rho,
                                                 const float* __restrict__ qneutral,
                                                 float* __restrict__ ep_all,
                                                 float* __restrict__ ener2_a,
                                                 float* __restrict__ erep_a){
  __shared__ float sRed[256];
  __shared__ float sdQ[64];
  __shared__ float sEp[64];
  const int mol = blockIdx.x;
  const int t = threadIdx.x;
  const int i = t >> 2, q4 = t & 3;
  const float* Sm = S   + (size_t)mol * 4096;
  const float* Gm = G   + (size_t)mol * 4096;
  const float* Rm = rho + (size_t)mol * 4096;

  float acc = 0.f;
  {
    const float4* S4 = reinterpret_cast<const float4*>(Sm + i*64 + q4*16);
    const float4* R4 = reinterpret_cast<const float4*>(Rm + i*64 + q4*16);
    #pragma unroll
    for (int m = 0; m < 4; ++m){
      float4 sv = S4[m], rv = R4[m];
      acc += sv.x*rv.x + sv.y*rv.y + sv.z*rv.z + sv.w*rv.w;
    }
  }
  sRed[t] = acc; __syncthreads();
  if (t < 64) sdQ[t] = qneutral[(size_t)mol*64 + t]
                       - (sRed[4*t] + sRed[4*t+1] + sRed[4*t+2] + sRed[4*t+3]);
  __syncthreads();

  float acc2 = 0.f;
  {
    const float4* G4 = reinterpret_cast<const float4*>(Gm + i*64 + q4*16);
    #pragma unroll
    for (int m = 0; m < 4; ++m){
      float4 gv = G4[m];
      int j0 = q4*16 + m*4;
      acc2 += gv.x*sdQ[j0] + gv.y*sdQ[j0+1] + gv.z*sdQ[j0+2] + gv.w*sdQ[j0+3];
    }
  }
  sRed[t] = acc2; __syncthreads();
  if (t < 64){
    float e = sRed[4*t] + sRed[4*t+1] + sRed[4*t+2] + sRed[4*t+3];
    sEp[t] = e;
    ep_all[(size_t)mol*64 + t] = e;
  }
  __syncthreads();
  if (t == 0){
    float s = 0.f;
    for (int j = 0; j < 64; ++j) s += sdQ[j] * sEp[j];
    ener2_a[mol] = 0.5f * s;
    erep_a[mol]  = 0.f;
  }
}

// ---------------- K4: Erep segment sum (sorted seg ids) ----------------
__global__ __launch_bounds__(256) void k_erep(const float* __restrict__ net,
                                              const int* __restrict__ g_rep,
                                              const int* __restrict__ seg_ids,
                                              float* __restrict__ erep_a){
  const int CH = 64;
  long tid = (long)blockIdx.x * 256 + threadIdx.x;
  long start = tid * CH;
  if (start >= NREPC) return;
  long end = start + CH; if (end > NREPC) end = NREPC;
  int cur = seg_ids[start];
  float acc = 0.f;
  for (long e = start; e < end; ++e){
    int sgid = seg_ids[e];
    if (sgid != cur){ atomicAdd(&erep_a[cur], acc); cur = sgid; acc = 0.f; }
    acc += net[g_rep[e]];
  }
  atomicAdd(&erep_a[cur], acc);
}

// ---------------- LDS matmul helper (64x64, stride MS), A symmetric ------
__device__ __forceinline__ void mm_symA(float (*__restrict__ D)[MS],
                                        const float (*__restrict__ A)[MS],
                                        const float (*__restrict__ B)[MS],
                                        float alpha, float diag, int t){
  const int r0 = (t & 15) << 2, c0 = (t >> 4) << 2;
  float acc[4][4];
  #pragma unroll
  for (int i = 0; i < 4; ++i)
    #pragma unroll
    for (int j = 0; j < 4; ++j) acc[i][j] = 0.f;
  #pragma unroll 8
  for (int k = 0; k < 64; ++k){
    float4 av = *reinterpret_cast<const float4*>(&A[k][r0]);
    float4 bv = *reinterpret_cast<const float4*>(&B[k][c0]);
    float a_[4] = {av.x, av.y, av.z, av.w};
    float b_[4] = {bv.x, bv.y, bv.z, bv.w};
    #pragma unroll
    for (int i = 0; i < 4; ++i)
      #pragma unroll
      for (int j = 0; j < 4; ++j)
        acc[i][j] += a_[i] * b_[j];
  }
  #pragma unroll
  for (int i = 0; i < 4; ++i)
    #pragma unroll
    for (int j = 0; j < 4; ++j)
      D[r0+i][c0+j] = alpha * acc[i][j] + ((r0+i) == (c0+j) ? diag : 0.f);
}

// ---- K5: NS X=S^{-1/2} (6 mm) + fockp = X F X + C2 = X E S X (4 mm) -----
__global__ __launch_bounds__(256, 2) void k_ns(const float* __restrict__ S,
                                               const int* __restrict__ g_oper,
                                               const float* __restrict__ rot_out,
                                               const float* __restrict__ ep_all,
                                               float* __restrict__ fockp_all,
                                               float* __restrict__ C2_all){
  __shared__ float M[4][64][MS];
  __shared__ float sEp[64];
  const int t   = threadIdx.x;
  const int mol = blockIdx.x;
  const float* Sm = S + (size_t)mol * 4096;
  const int*   gm = g_oper + (size_t)mol * 4096;

  // init: M0 = S, M2 = 3I - S
  #pragma unroll
  for (int m = 0; m < 16; ++m){
    int e = t + (m << 8);
    int i = e >> 6, j = e & 63;
    float s = Sm[e];
    M[0][i][j] = s;
    M[2][i][j] = ((i == j) ? 3.f : 0.f) - s;
  }
  if (t < 64) sEp[t] = ep_all[(size_t)mol*64 + t];
  __syncthreads();
  mm_symA(M[3], M[0], M[2], 0.5f, 0.f, t);          // Y1 = 0.5 S (3I-S)
  #pragma unroll
  for (int m = 0; m < 16; ++m){
    int e = t + (m << 8);
    M[1][e >> 6][e & 63] = 0.5f * M[2][e >> 6][e & 63];  // Z1 = 0.5(3I-S)
  }
  __syncthreads();
  // iter2: Y=M3, Z=M1
  mm_symA(M[0], M[1], M[3], -1.f, 3.f, t); __syncthreads();  // T2 = 3I - Z1*Y1
  mm_symA(M[2], M[3], M[0], 0.5f, 0.f, t); __syncthreads();  // Y2 = 0.5*Y1*T2
  mm_symA(M[3], M[0], M[1], 0.5f, 0.f, t); __syncthreads();  // Z2 = 0.5*T2*Z1
  // iter3 (Z-only): Y=M2, Z=M3
  mm_symA(M[1], M[3], M[2], -1.f, 3.f, t); __syncthreads();  // T3 = 3I - Z2*Y2
  mm_symA(M[0], M[1], M[3], 0.5f, 0.f, t); __syncthreads();  // X  = 0.5*T3*Z2
  // buffers now: M0 = X; M1..M3 free

  // --- H gather -> M1 ---
  #pragma unroll
  for (int m = 0; m < 16; ++m){
    int e = t + (m << 8);
    M[1][e >> 6][e & 63] = rot_out[gm[e]];
  }
  __syncthreads();
  // --- F -> M2: F_ij = 0.5(H_ij + H_ji) - 0.5 S_ij (ep_i + ep_j) ---
  #pragma unroll
  for (int m = 0; m < 16; ++m){
    int e = t + (m << 8);
    int i = e >> 6, j = e & 63;
    M[2][i][j] = 0.5f*(M[1][i][j] + M[1][j][i]) - 0.5f*Sm[e]*(sEp[i] + sEp[j]);
  }
  __syncthreads();
  mm_symA(M[3], M[2], M[0], 1.f, 0.f, t); __syncthreads();  // P1 = F*X
  mm_symA(M[1], M[0], M[3], 1.f, 0.f, t); __syncthreads();  // fockp = X*P1
  #pragma unroll
  for (int m = 0; m < 16; ++m){
    int e = t + (m << 8);
    fockp_all[(size_t)mol * 4096 + e] = M[1][e >> 6][e & 63];
  }
  // --- reload S -> M2 ---
  #pragma unroll
  for (int m = 0; m < 16; ++m){
    int e = t + (m << 8);
    M[2][e >> 6][e & 63] = Sm[e];
  }
  __syncthreads();
  mm_symA(M[3], M[2], M[0], 1.f, 0.f, t); __syncthreads();  // C1 = S*X
  // EC1 in place: row-scale by ep
  #pragma unroll
  for (int m = 0; m < 16; ++m){
    int e = t + (m << 8);
    int i = e >> 6, j = e & 63;
    M[3][i][j] *= sEp[i];
  }
  __syncthreads();
  mm_symA(M[1], M[0], M[3], 1.f, 0.f, t); __syncthreads();  // C2 = X*(E C1)
  #pragma unroll
  for (int m = 0; m < 16; ++m){
    int e = t + (m << 8);
    C2_all[(size_t)mol * 4096 + e] = M[1][e >> 6][e & 63];
  }
}

// ---------------- K6: split-row XOR-block Jacobi + split epilogue ---------
__global__ __launch_bounds__(64, 2) void k_jac(const float* __restrict__ fockp_all,
                                               const float* __restrict__ C2_all,
                                               const float* __restrict__ ener2_a,
                                               const float* __restrict__ erep_a,
                                               float* __restrict__ out){
  __shared__ float Bl[64 * 68];         // C2 staging (pre-loaded before sweeps)
  const int lane = threadIdx.x;
  const int mol  = blockIdx.x;
  const float* Am = fockp_all + (size_t)mol * 4096;
  const float* Cm = C2_all    + (size_t)mol * 4096;
  const int pid  = lane & 31;
  const int half = lane >> 5;

  // --- direct split-layout load: proc pid = lanes (pid, pid+32);
  //     lane holds rows [half*32, half*32+32) of cols A=pid, B=32+pid ---
  float Ac[32], Bc[32];
  float csA = 0.f, csB = 0.f;
  #pragma unroll
  for (int i = 0; i < 32; ++i){
    float a = Am[(half*32 + i)*64 + pid];
    float b = Am[(half*32 + i)*64 + 32 + pid];
    Ac[i] = a; Bc[i] = b;
    csA += fabsf(a); csB += fabsf(b);
  }
  // --- stage C2 into LDS now; latency hides under the Jacobi sweeps ---
  #pragma unroll
  for (int i = 0; i < 64; ++i) Bl[i*68 + lane] = Cm[i*64 + lane];

  // --- Gershgorin shift: mu = 1.02 * max col abs-sum; add to diagonals ---
  csA += __shfl_xor(csA, 32);
  csB += __shfl_xor(csB, 32);
  float mu = fmaxf(csA, csB);
  #pragma unroll
  for (int d = 1; d < 32; d <<= 1) mu = fmaxf(mu, __shfl_xor(mu, d));
  mu *= 1.02f;
  #pragma unroll
  for (int i = 0; i < 32; ++i){
    Ac[i] += (half == 0 && i == pid) ? mu : 0.f;
    Bc[i] += (half == 1 && i == pid) ? mu : 0.f;
  }

  // --- XOR-block one-sided Jacobi (r10-measured loop; layout-invariant) ---
  for (int sweep = 0; sweep < 4; ++sweep){
    float al = 0.f, bl = 0.f;
    #pragma unroll
    for (int i = 0; i < 32; ++i){
      al = fmaf(Ac[i], Ac[i], al);
      bl = fmaf(Bc[i], Bc[i], bl);
    }
    float alpha = al + __shfl_xor(al, 32);
    float beta  = bl + __shfl_xor(bl, 32);

    unsigned long long any = 0ULL;
    for (int j = 5; j >= 0; --j){
      const int M = 1 << j;
      for (int k = 0; k < M; ++k){
        float gl = 0.f;
        #pragma unroll
        for (int i = 0; i < 32; ++i) gl = fmaf(Ac[i], Bc[i], gl);
        float gamma = gl + __shfl_xor(gl, 32);
        bool rot = (gamma * gamma) > (1e-9f * alpha * beta);
        unsigned long long bal = __ballot(rot);
        any |= bal;
        if (bal != 0ULL){
          float tau = (beta - alpha) / (2.f * gamma);
          float tq  = copysignf(1.f, tau) / (fabsf(tau) + sqrtf(fmaf(tau, tau, 1.f)));
          float c = rsqrtf(fmaf(tq, tq, 1.f));
          float s = tq * c;
          if (!rot){ c = 1.f; s = 0.f; }
          float na = c*c*alpha + s*s*beta - 2.f*c*s*gamma;
          float nb = s*s*alpha + c*c*beta + 2.f*c*s*gamma;
          alpha = na; beta = nb;
          #pragma unroll
          for (int i = 0; i < 32; ++i){
            float ta = Ac[i];
            Ac[i] = fmaf(-s, Bc[i], c * ta);
            Bc[i] = fmaf( c, Bc[i], s * ta);
          }
        }
        if (k < M - 1){
          int e  = k ^ (k >> 1);
          int e2 = (k + 1) ^ ((k + 1) >> 1);
          int mig = e ^ e2;
          #pragma unroll
          for (int i = 0; i < 32; ++i) Bc[i] = __shfl_xor(Bc[i], mig);
          beta = __shfl_xor(beta, mig);
        } else if (j > 0){
          const int Mp = M >> 1;
          const bool hb = (pid & Mp) != 0;
          #pragma unroll
          for (int i = 0; i < 32; ++i){
            float send = hb ? Ac[i] : Bc[i];
            float recv = __shfl_xor(send, Mp);
            Ac[i] = hb ? Bc[i] : Ac[i];
            Bc[i] = recv;
          }
          float sendb = hb ? alpha : beta;
          float recvb = __shfl_xor(sendb, Mp);
          alpha = hb ? beta : alpha;
          beta  = recvb;
        }
      }
    }
    if (any == 0ULL) break;
  }

  // --- split-form epilogue: NO reassembly, no w[64] ---
  // column norms -> eigenvalues (lane <32 owns col A(pid); lane>=32 col B(pid))
  float nA = 0.f, nB = 0.f;
  #pragma unroll
  for (int i = 0; i < 32; ++i){
    nA = fmaf(Ac[i], Ac[i], nA);
    nB = fmaf(Bc[i], Bc[i], nB);
  }
  nA += __shfl_xor(nA, 32);
  nB += __shfl_xor(nB, 32);
  float myLamS = half ? sqrtf(nB) : sqrtf(nA);
  float myLam  = myLamS - mu;

  int rank = 0;
  for (int k = 0; k < 64; ++k){
    float lk = __shfl(myLam, k);
    rank += (lk < myLam || (lk == myLam && k < lane)) ? 1 : 0;
  }
  out[(size_t)mol*65 + 1 + rank] = myLam;

  float occf = (rank < 32) ? 1.f : 0.f;
  float slam = occf * myLam;
  #pragma unroll
  for (int d = 1; d < 64; d <<= 1) slam += __shfl_xor(slam, d);

  // per-column scales: col A's scale lives on lane pid, col B's on lane 32+pid
  float myScale = occf / myLamS;
  float sA = __shfl(myScale, pid);
  float sB = __shfl(myScale, 32 + pid);
  #pragma unroll
  for (int i = 0; i < 32; ++i){ Ac[i] *= sA; Bc[i] *= sB; }

  __syncthreads();   // C2 staging visible (single wave: cheap)

  // quadratic form in split layout:
  // term += sum_{i in myhalf} v_i * (sum_k C2[r_i, k] v_k), v split as
  // (my 32 rows = Ac/Bc, partner 32 rows via one shfl_xor(.,32) per element)
  const int myB = half * 32;       // my row/col block offset
  const int otB = 32 - myB;        // partner block offset
  float pv[32];
  float term = 0.f;
  #pragma unroll
  for (int i = 0; i < 32; ++i) pv[i] = __shfl_xor(Ac[i], 32);
  #pragma unroll 4
  for (int i = 0; i < 32; ++i){
    const float* row = &Bl[(myB + i) * 68];
    float d = 0.f;
    #pragma unroll
    for (int k = 0; k < 32; k += 4){
      float4 c1 = *reinterpret_cast<const float4*>(&row[myB + k]);
      d = fmaf(c1.x, Ac[k], d);   d = fmaf(c1.y, Ac[k+1], d);
      d = fmaf(c1.z, Ac[k+2], d); d = fmaf(c1.w, Ac[k+3], d);
      float4 c2 = *reinterpret_cast<const float4*>(&row[otB + k]);
      d = fmaf(c2.x, pv[k], d);   d = fmaf(c2.y, pv[k+1], d);
      d = fmaf(c2.z, pv[k+2], d); d = fmaf(c2.w, pv[k+3], d);
    }
    term = fmaf(Ac[i], d, term);
  }
  #pragma unroll
  for (int i = 0; i < 32; ++i) pv[i] = __shfl_xor(Bc[i], 32);
  #pragma unroll 4
  for (int i = 0; i < 32; ++i){
    const float* row = &Bl[(myB + i) * 68];
    float d = 0.f;
    #pragma unroll
    for (int k = 0; k < 32; k += 4){
      float4 c1 = *reinterpret_cast<const float4*>(&row[myB + k]);
      d = fmaf(c1.x, Bc[k], d);   d = fmaf(c1.y, Bc[k+1], d);
      d = fmaf(c1.z, Bc[k+2], d); d = fmaf(c1.w, Bc[k+3], d);
      float4 c2 = *reinterpret_cast<const float4*>(&row[otB + k]);
      d = fmaf(c2.x, pv[k], d);   d = fmaf(c2.y, pv[k+1], d);
      d = fmaf(c2.z, pv[k+2], d); d = fmaf(c2.w, pv[k+3], d);
    }
    term = fmaf(Bc[i], d, term);
  }
  #pragma unroll
  for (int d2 = 1; d2 < 64; d2 <<= 1) term += __shfl_xor(term, d2);

  if (lane == 0){
    out[(size_t)mol*65] = 2.f*slam + 2.f*term + ener2_a[mol] + erep_a[mol];
  }
}

// ---------------------------------------------------------------------------
extern "C" void kernel_launch(void* const* d_in, const int* in_sizes, int n_in,
                              void* d_out, int out_size, void* d_ws, size_t ws_size,
                              hipStream_t stream){
  (void)in_sizes; (void)n_in; (void)out_size; (void)ws_size;
  const float* A          = (const float*)d_in[0];
  const float* b          = (const float*)d_in[1];
  const float* coeffs     = (const float*)d_in[2];
  const float* rot_tensor = (const float*)d_in[3];
  const float* S          = (const float*)d_in[4];
  const float* G          = (const float*)d_in[5];
  const float* rho        = (const float*)d_in[6];
  const float* qneutral   = (const float*)d_in[7];
  const int* g_rot_direct = (const int*)d_in[9];
  const int* g_rot        = (const int*)d_in[10];
  const int* g_oper       = (const int*)d_in[11];
  const int* g_rep        = (const int*)d_in[12];
  const int* seg_ids      = (const int*)d_in[13];
  float* out = (float*)d_out;

  // ws layout (floats): 5.35MB scalars + fockp 32MB + C2 32MB ~= 72.5MB
  float* W         = (float*)d_ws;
  float* net       = W;                    // 500000
  float* rot_out   = W + 500000;           // 700002 (padded to 700004)
  float* ep_all    = W + 1200004;          // 2048*64
  float* ener2_a   = W + 1331076;          // 2048
  float* erep_a    = W + 1333124;          // 2048
  float* fockp_all = W + 1335172;          // 2048*4096
  float* C2_all    = W + 9723780;          // 2048*4096 (ends 18112388)

  k_netvals<<<(NSPC*16)/256, 256, 0, stream>>>(A, b, coeffs, net);
  k_rot<<<(L0C + NROTC + 255)/256, 256, 0, stream>>>(net, rot_tensor, g_rot_direct, g_rot, rot_out);
  k_coulomb<<<NMOLC, 256, 0, stream>>>(S, G, rho, qneutral, ep_all, ener2_a, erep_a);
  k_erep<<<((NREPC + 63)/64 + 255)/256, 256, 0, stream>>>(net, g_rep, seg_ids, erep_a);
  k_ns<<<NMOLC, 256, 0, stream>>>(S, g_oper, rot_out, ep_all, fockp_all, C2_all);
  k_jac<<<NMOLC, 64, 0, stream>>>(fockp_all, C2_all, ener2_a, erep_a, out);
}

// Round 13
// 513.918 us; speedup vs baseline: 3.0526x; 1.1337x over previous
//
#include <hip/hip_runtime.h>

// ---------------------------------------------------------------------------
// DFTB layer, round 13.
//  K1 netvals / K2 rot / K3 coulomb / K4 erep  (unchanged)
//  K5 k_ns  : NS S^{-1/2} (6 mm) + fockp = X F X + C2 = X E S X (4 mm)
//  K6 k_jac : split-row XOR-block Jacobi + split epilogue (r12-measured,
//             no spill). Round-13 changes INSIDE the sweep loop only:
//              - three-shear rotation (exact, 3 FMA/elem-pair vs 4 VALU)
//              - 4-way split gamma/norm chains (latency 128cy -> ~40cy)
//              - native v_rcp/v_rsq for the angle chain (self-correcting)
//              - sweeps 4 -> 3 (absmax bit-identical at 5 and 4 sweeps;
//                pre-commit: revert to 4 if absmax degrades)
// ---------------------------------------------------------------------------

#define NMOLC 2048
#define NSPC  500000
#define L0C   100000
#define NROTC 200000
#define NREPC 500000
#define MS 68   // LDS row stride for k_ns matmul buffers

// ---------------- K1: net_vals = A @ coeffs + b ----------------
__global__ __launch_bounds__(256) void k_netvals(const float* __restrict__ A,
                                                 const float* __restrict__ b,
                                                 const float* __restrict__ coeffs,
                                                 float* __restrict__ net){
  int gid = blockIdx.x * 256 + threadIdx.x;
  int row = gid >> 4;
  int l   = gid & 15;
  if (row >= NSPC) return;
  float4 c4 = reinterpret_cast<const float4*>(coeffs)[l];
  float4 a4 = reinterpret_cast<const float4*>(A)[(size_t)row * 16 + l];
  float s = a4.x*c4.x + a4.y*c4.y + a4.z*c4.z + a4.w*c4.w;
  s += __shfl_xor(s, 1, 16);
  s += __shfl_xor(s, 2, 16);
  s += __shfl_xor(s, 4, 16);
  s += __shfl_xor(s, 8, 16);
  if (l == 0) net[row] = s + b[row];
}

// ---------------- K2: rot_out = [0,1] ++ direct ++ rotated ----------------
__global__ __launch_bounds__(256) void k_rot(const float* __restrict__ net,
                                             const float* __restrict__ rot_tensor,
                                             const int* __restrict__ g_rot_direct,
                                             const int* __restrict__ g_rot,
                                             float* __restrict__ rot_out){
  int gid = blockIdx.x * 256 + threadIdx.x;
  if (gid == 0){ rot_out[0] = 0.f; rot_out[1] = 1.f; }
  if (gid < L0C){
    rot_out[2 + gid] = net[g_rot_direct[gid]];
  }
  int n = gid - L0C;
  if (n >= 0 && n < NROTC){
    float v0 = net[g_rot[3*n    ]];
    float v1 = net[g_rot[3*n + 1]];
    float v2 = net[g_rot[3*n + 2]];
    const float* R = rot_tensor + (size_t)9 * n;
    float* o = rot_out + 2 + L0C + 3*n;
    o[0] = R[0]*v0 + R[1]*v1 + R[2]*v2;
    o[1] = R[3]*v0 + R[4]*v1 + R[5]*v2;
    o[2] = R[6]*v0 + R[7]*v1 + R[8]*v2;
  }
}

// ---------------- K3: dQ, ep = G@dQ, ener2; zero erep ----------------
__global__ __launch_bounds__(256) void k_coulomb(const float* __restrict__ S,
                                                 const float* __restrict__ G,
                                                 const float* __restrict__ rho,
                                                 const float* __restrict__ qneutral,
                                                 float* __restrict__ ep_all,
                                                 float* __restrict__ ener2_a,
                                                 float* __restrict__ erep_a){
  __shared__ float sRed[256];
  __shared__ float sdQ[64];
  __shared__ float sEp[64];
  const int mol = blockIdx.x;
  const int t = threadIdx.x;
  const int i = t >> 2, q4 = t & 3;
  const float* Sm = S   + (size_t)mol * 4096;
  const float* Gm = G   + (size_t)mol * 4096;
  const float* Rm = rho + (size_t)mol * 4096;

  float acc = 0.f;
  {
    const float4* S4 = reinterpret_cast<const float4*>(Sm + i*64 + q4*16);
    const float4* R4 = reinterpret_cast<const float4*>(Rm + i*64 + q4*16);
    #pragma unroll
    for (int m = 0; m < 4; ++m){
      float4 sv = S4[m], rv = R4[m];
      acc += sv.x*rv.x + sv.y*rv.y + sv.z*rv.z + sv.w*rv.w;
    }
  }
  sRed[t] = acc; __syncthreads();
  if (t < 64) sdQ[t] = qneutral[(size_t)mol*64 + t]
                       - (sRed[4*t] + sRed[4*t+1] + sRed[4*t+2] + sRed[4*t+3]);
  __syncthreads();

  float acc2 = 0.f;
  {
    const float4* G4 = reinterpret_cast<const float4*>(Gm + i*64 + q4*16);
    #pragma unroll
    for (int m = 0; m < 4; ++m){
      float4 gv = G4[m];
      int j0 = q4*16 + m*4;
      acc2 += gv.x*sdQ[j0] + gv.y*sdQ[j0+1] + gv.z*sdQ[j0+2] + gv.w*sdQ[j0+3];
    }
  }
  sRed[t] = acc2; __syncthreads();
  if (t < 64){
    float e = sRed[4*t] + sRed[4*t+1] + sRed[4*t+2] + sRed[4*t+3];
    sEp[t] = e;
    ep_all[(size_t)mol*64 + t] = e;
  }
  __syncthreads();
  if (t == 0){
    float s = 0.f;
    for (int j = 0; j < 64; ++j) s += sdQ[j] * sEp[j];
    ener2_a[mol] = 0.5f * s;
    erep_a[mol]  = 0.f;
  }
}

// ---------------- K4: Erep segment sum (sorted seg ids) ----------------
__global__ __launch_bounds__(256) void k_erep(const float* __restrict__ net,
                                              const int* __restrict__ g_rep,
                                              const int* __restrict__ seg_ids,
                                              float* __restrict__ erep_a){
  const int CH = 64;
  long tid = (long)blockIdx.x * 256 + threadIdx.x;
  long start = tid * CH;
  if (start >= NREPC) return;
  long end = start + CH; if (end > NREPC) end = NREPC;
  int cur = seg_ids[start];
  float acc = 0.f;
  for (long e = start; e < end; ++e){
    int sgid = seg_ids[e];
    if (sgid != cur){ atomicAdd(&erep_a[cur], acc); cur = sgid; acc = 0.f; }
    acc += net[g_rep[e]];
  }
  atomicAdd(&erep_a[cur], acc);
}

// ---------------- LDS matmul helper (64x64, stride MS), A symmetric ------
__device__ __forceinline__ void mm_symA(float (*__restrict__ D)[MS],
                                        const float (*__restrict__ A)[MS],
                                        const float (*__restrict__ B)[MS],
                                        float alpha, float diag, int t){
  const int r0 = (t & 15) << 2, c0 = (t >> 4) << 2;
  float acc[4][4];
  #pragma unroll
  for (int i = 0; i < 4; ++i)
    #pragma unroll
    for (int j = 0; j < 4; ++j) acc[i][j] = 0.f;
  #pragma unroll 8
  for (int k = 0; k < 64; ++k){
    float4 av = *reinterpret_cast<const float4*>(&A[k][r0]);
    float4 bv = *reinterpret_cast<const float4*>(&B[k][c0]);
    float a_[4] = {av.x, av.y, av.z, av.w};
    float b_[4] = {bv.x, bv.y, bv.z, bv.w};
    #pragma unroll
    for (int i = 0; i < 4; ++i)
      #pragma unroll
      for (int j = 0; j < 4; ++j)
        acc[i][j] += a_[i] * b_[j];
  }
  #pragma unroll
  for (int i = 0; i < 4; ++i)
    #pragma unroll
    for (int j = 0; j < 4; ++j)
      D[r0+i][c0+j] = alpha * acc[i][j] + ((r0+i) == (c0+j) ? diag : 0.f);
}

// ---- K5: NS X=S^{-1/2} (6 mm) + fockp = X F X + C2 = X E S X (4 mm) -----
__global__ __launch_bounds__(256, 2) void k_ns(const float* __restrict__ S,
                                               const int* __restrict__ g_oper,
                                               const float* __restrict__ rot_out,
                                               const float* __restrict__ ep_all,
                                               float* __restrict__ fockp_all,
                                               float* __restrict__ C2_all){
  __shared__ float M[4][64][MS];
  __shared__ float sEp[64];
  const int t   = threadIdx.x;
  const int mol = blockIdx.x;
  const float* Sm = S + (size_t)mol * 4096;
  const int*   gm = g_oper + (size_t)mol * 4096;

  // init: M0 = S, M2 = 3I - S
  #pragma unroll
  for (int m = 0; m < 16; ++m){
    int e = t + (m << 8);
    int i = e >> 6, j = e & 63;
    float s = Sm[e];
    M[0][i][j] = s;
    M[2][i][j] = ((i == j) ? 3.f : 0.f) - s;
  }
  if (t < 64) sEp[t] = ep_all[(size_t)mol*64 + t];
  __syncthreads();
  mm_symA(M[3], M[0], M[2], 0.5f, 0.f, t);          // Y1 = 0.5 S (3I-S)
  #pragma unroll
  for (int m = 0; m < 16; ++m){
    int e = t + (m << 8);
    M[1][e >> 6][e & 63] = 0.5f * M[2][e >> 6][e & 63];  // Z1 = 0.5(3I-S)
  }
  __syncthreads();
  // iter2: Y=M3, Z=M1
  mm_symA(M[0], M[1], M[3], -1.f, 3.f, t); __syncthreads();  // T2 = 3I - Z1*Y1
  mm_symA(M[2], M[3], M[0], 0.5f, 0.f, t); __syncthreads();  // Y2 = 0.5*Y1*T2
  mm_symA(M[3], M[0], M[1], 0.5f, 0.f, t); __syncthreads();  // Z2 = 0.5*T2*Z1
  // iter3 (Z-only): Y=M2, Z=M3
  mm_symA(M[1], M[3], M[2], -1.f, 3.f, t); __syncthreads();  // T3 = 3I - Z2*Y2
  mm_symA(M[0], M[1], M[3], 0.5f, 0.f, t); __syncthreads();  // X  = 0.5*T3*Z2
  // buffers now: M0 = X; M1..M3 free

  // --- H gather -> M1 ---
  #pragma unroll
  for (int m = 0; m < 16; ++m){
    int e = t + (m << 8);
    M[1][e >> 6][e & 63] = rot_out[gm[e]];
  }
  __syncthreads();
  // --- F -> M2: F_ij = 0.5(H_ij + H_ji) - 0.5 S_ij (ep_i + ep_j) ---
  #pragma unroll
  for (int m = 0; m < 16; ++m){
    int e = t + (m << 8);
    int i = e >> 6, j = e & 63;
    M[2][i][j] = 0.5f*(M[1][i][j] + M[1][j][i]) - 0.5f*Sm[e]*(sEp[i] + sEp[j]);
  }
  __syncthreads();
  mm_symA(M[3], M[2], M[0], 1.f, 0.f, t); __syncthreads();  // P1 = F*X
  mm_symA(M[1], M[0], M[3], 1.f, 0.f, t); __syncthreads();  // fockp = X*P1
  #pragma unroll
  for (int m = 0; m < 16; ++m){
    int e = t + (m << 8);
    fockp_all[(size_t)mol * 4096 + e] = M[1][e >> 6][e & 63];
  }
  // --- reload S -> M2 ---
  #pragma unroll
  for (int m = 0; m < 16; ++m){
    int e = t + (m << 8);
    M[2][e >> 6][e & 63] = Sm[e];
  }
  __syncthreads();
  mm_symA(M[3], M[2], M[0], 1.f, 0.f, t); __syncthreads();  // C1 = S*X
  // EC1 in place: row-scale by ep
  #pragma unroll
  for (int m = 0; m < 16; ++m){
    int e = t + (m << 8);
    int i = e >> 6, j = e & 63;
    M[3][i][j] *= sEp[i];
  }
  __syncthreads();
  mm_symA(M[1], M[0], M[3], 1.f, 0.f, t); __syncthreads();  // C2 = X*(E C1)
  #pragma unroll
  for (int m = 0; m < 16; ++m){
    int e = t + (m << 8);
    C2_all[(size_t)mol * 4096 + e] = M[1][e >> 6][e & 63];
  }
}

// ---------------- K6: split-row XOR-block Jacobi + split epilogue ---------
__global__ __launch_bounds__(64, 2) void k_jac(const float* __restrict__ fockp_all,
                                               const float* __restrict__ C2_all,
                                               const float* __restrict__ ener2_a,
                                               const float* __restrict__ erep_a,
                                               float* __restrict__ out){
  __shared__ float Bl[64 * 68];         // C2 staging (pre-loaded before sweeps)
  const int lane = threadIdx.x;
  const int mol  = blockIdx.x;
  const float* Am = fockp_all + (size_t)mol * 4096;
  const float* Cm = C2_all    + (size_t)mol * 4096;
  const int pid  = lane & 31;
  const int half = lane >> 5;

  // --- direct split-layout load: proc pid = lanes (pid, pid+32);
  //     lane holds rows [half*32, half*32+32) of cols A=pid, B=32+pid ---
  float Ac[32], Bc[32];
  float csA = 0.f, csB = 0.f;
  #pragma unroll
  for (int i = 0; i < 32; ++i){
    float a = Am[(half*32 + i)*64 + pid];
    float b = Am[(half*32 + i)*64 + 32 + pid];
    Ac[i] = a; Bc[i] = b;
    csA += fabsf(a); csB += fabsf(b);
  }
  // --- stage C2 into LDS now; latency hides under the Jacobi sweeps ---
  #pragma unroll
  for (int i = 0; i < 64; ++i) Bl[i*68 + lane] = Cm[i*64 + lane];

  // --- Gershgorin shift: mu = 1.02 * max col abs-sum; add to diagonals ---
  csA += __shfl_xor(csA, 32);
  csB += __shfl_xor(csB, 32);
  float mu = fmaxf(csA, csB);
  #pragma unroll
  for (int d = 1; d < 32; d <<= 1) mu = fmaxf(mu, __shfl_xor(mu, d));
  mu *= 1.02f;
  #pragma unroll
  for (int i = 0; i < 32; ++i){
    Ac[i] += (half == 0 && i == pid) ? mu : 0.f;
    Bc[i] += (half == 1 && i == pid) ? mu : 0.f;
  }

  // --- XOR-block one-sided Jacobi (layout-invariant schedule);
  //     three-shear rotations, 4-way dot chains, native rcp/rsq ---
  for (int sweep = 0; sweep < 3; ++sweep){
    float a0 = 0.f, a1 = 0.f, a2 = 0.f, a3 = 0.f;
    float b0 = 0.f, b1 = 0.f, b2 = 0.f, b3 = 0.f;
    #pragma unroll
    for (int i = 0; i < 32; i += 4){
      a0 = fmaf(Ac[i],   Ac[i],   a0); a1 = fmaf(Ac[i+1], Ac[i+1], a1);
      a2 = fmaf(Ac[i+2], Ac[i+2], a2); a3 = fmaf(Ac[i+3], Ac[i+3], a3);
      b0 = fmaf(Bc[i],   Bc[i],   b0); b1 = fmaf(Bc[i+1], Bc[i+1], b1);
      b2 = fmaf(Bc[i+2], Bc[i+2], b2); b3 = fmaf(Bc[i+3], Bc[i+3], b3);
    }
    float alpha = (a0 + a1) + (a2 + a3);
    float beta  = (b0 + b1) + (b2 + b3);
    alpha += __shfl_xor(alpha, 32);
    beta  += __shfl_xor(beta, 32);

    unsigned long long any = 0ULL;
    for (int j = 5; j >= 0; --j){
      const int M = 1 << j;
      for (int k = 0; k < M; ++k){
        float g0 = 0.f, g1 = 0.f, g2 = 0.f, g3 = 0.f;
        #pragma unroll
        for (int i = 0; i < 32; i += 4){
          g0 = fmaf(Ac[i],   Bc[i],   g0);
          g1 = fmaf(Ac[i+1], Bc[i+1], g1);
          g2 = fmaf(Ac[i+2], Bc[i+2], g2);
          g3 = fmaf(Ac[i+3], Bc[i+3], g3);
        }
        float gamma = (g0 + g1) + (g2 + g3);
        gamma += __shfl_xor(gamma, 32);
        bool rot = (gamma * gamma) > (1e-9f * alpha * beta);
        unsigned long long bal = __ballot(rot);
        any |= bal;
        if (bal != 0ULL){
          // angle chain on native rcp/rsq (Jacobi self-corrects ULP error)
          float tau = (beta - alpha) * 0.5f * __builtin_amdgcn_rcpf(gamma);
          float tq  = copysignf(1.f, tau) *
                      __builtin_amdgcn_rcpf(fabsf(tau) + __builtin_amdgcn_sqrtf(fmaf(tau, tau, 1.f)));
          float c = __builtin_amdgcn_rsqf(fmaf(tq, tq, 1.f));
          float s = tq * c;
          float th = s * __builtin_amdgcn_rcpf(1.f + c);   // tan(theta/2)
          if (!rot){ c = 1.f; s = 0.f; th = 0.f; }
          float na = c*c*alpha + s*s*beta - 2.f*c*s*gamma;
          float nb = s*s*alpha + c*c*beta + 2.f*c*s*gamma;
          alpha = na; beta = nb;
          // three-shear rotation: exact det-1, 3 FMA per element pair
          #pragma unroll
          for (int i = 0; i < 32; ++i) Ac[i] = fmaf(-th, Bc[i], Ac[i]);
          #pragma unroll
          for (int i = 0; i < 32; ++i) Bc[i] = fmaf( s,  Ac[i], Bc[i]);
          #pragma unroll
          for (int i = 0; i < 32; ++i) Ac[i] = fmaf(-th, Bc[i], Ac[i]);
        }
        if (k < M - 1){
          int e  = k ^ (k >> 1);
          int e2 = (k + 1) ^ ((k + 1) >> 1);
          int mig = e ^ e2;
          #pragma unroll
          for (int i = 0; i < 32; ++i) Bc[i] = __shfl_xor(Bc[i], mig);
          beta = __shfl_xor(beta, mig);
        } else if (j > 0){
          const int Mp = M >> 1;
          const bool hb = (pid & Mp) != 0;
          #pragma unroll
          for (int i = 0; i < 32; ++i){
            float send = hb ? Ac[i] : Bc[i];
            float recv = __shfl_xor(send, Mp);
            Ac[i] = hb ? Bc[i] : Ac[i];
            Bc[i] = recv;
          }
          float sendb = hb ? alpha : beta;
          float recvb = __shfl_xor(sendb, Mp);
          alpha = hb ? beta : alpha;
          beta  = recvb;
        }
      }
    }
    if (any == 0ULL) break;
  }

  // --- split-form epilogue: NO reassembly, no w[64] ---
  float nA0 = 0.f, nA1 = 0.f, nB0 = 0.f, nB1 = 0.f;
  #pragma unroll
  for (int i = 0; i < 32; i += 2){
    nA0 = fmaf(Ac[i],   Ac[i],   nA0);
    nA1 = fmaf(Ac[i+1], Ac[i+1], nA1);
    nB0 = fmaf(Bc[i],   Bc[i],   nB0);
    nB1 = fmaf(Bc[i+1], Bc[i+1], nB1);
  }
  float nA = nA0 + nA1, nB = nB0 + nB1;
  nA += __shfl_xor(nA, 32);
  nB += __shfl_xor(nB, 32);
  float myLamS = half ? sqrtf(nB) : sqrtf(nA);
  float myLam  = myLamS - mu;

  int rank = 0;
  for (int k = 0; k < 64; ++k){
    float lk = __shfl(myLam, k);
    rank += (lk < myLam || (lk == myLam && k < lane)) ? 1 : 0;
  }
  out[(size_t)mol*65 + 1 + rank] = myLam;

  float occf = (rank < 32) ? 1.f : 0.f;
  float slam = occf * myLam;
  #pragma unroll
  for (int d = 1; d < 64; d <<= 1) slam += __shfl_xor(slam, d);

  // per-column scales: col A's scale lives on lane pid, col B's on lane 32+pid
  float myScale = occf / myLamS;
  float sA = __shfl(myScale, pid);
  float sB = __shfl(myScale, 32 + pid);
  #pragma unroll
  for (int i = 0; i < 32; ++i){ Ac[i] *= sA; Bc[i] *= sB; }

  __syncthreads();   // C2 staging visible (single wave: cheap)

  // quadratic form in split layout
  const int myB = half * 32;       // my row/col block offset
  const int otB = 32 - myB;        // partner block offset
  float pv[32];
  float term = 0.f;
  #pragma unroll
  for (int i = 0; i < 32; ++i) pv[i] = __shfl_xor(Ac[i], 32);
  #pragma unroll 4
  for (int i = 0; i < 32; ++i){
    const float* row = &Bl[(myB + i) * 68];
    float d = 0.f;
    #pragma unroll
    for (int k = 0; k < 32; k += 4){
      float4 c1 = *reinterpret_cast<const float4*>(&row[myB + k]);
      d = fmaf(c1.x, Ac[k], d);   d = fmaf(c1.y, Ac[k+1], d);
      d = fmaf(c1.z, Ac[k+2], d); d = fmaf(c1.w, Ac[k+3], d);
      float4 c2 = *reinterpret_cast<const float4*>(&row[otB + k]);
      d = fmaf(c2.x, pv[k], d);   d = fmaf(c2.y, pv[k+1], d);
      d = fmaf(c2.z, pv[k+2], d); d = fmaf(c2.w, pv[k+3], d);
    }
    term = fmaf(Ac[i], d, term);
  }
  #pragma unroll
  for (int i = 0; i < 32; ++i) pv[i] = __shfl_xor(Bc[i], 32);
  #pragma unroll 4
  for (int i = 0; i < 32; ++i){
    const float* row = &Bl[(myB + i) * 68];
    float d = 0.f;
    #pragma unroll
    for (int k = 0; k < 32; k += 4){
      float4 c1 = *reinterpret_cast<const float4*>(&row[myB + k]);
      d = fmaf(c1.x, Bc[k], d);   d = fmaf(c1.y, Bc[k+1], d);
      d = fmaf(c1.z, Bc[k+2], d); d = fmaf(c1.w, Bc[k+3], d);
      float4 c2 = *reinterpret_cast<const float4*>(&row[otB + k]);
      d = fmaf(c2.x, pv[k], d);   d = fmaf(c2.y, pv[k+1], d);
      d = fmaf(c2.z, pv[k+2], d); d = fmaf(c2.w, pv[k+3], d);
    }
    term = fmaf(Bc[i], d, term);
  }
  #pragma unroll
  for (int d2 = 1; d2 < 64; d2 <<= 1) term += __shfl_xor(term, d2);

  if (lane == 0){
    out[(size_t)mol*65] = 2.f*slam + 2.f*term + ener2_a[mol] + erep_a[mol];
  }
}

// ---------------------------------------------------------------------------
extern "C" void kernel_launch(void* const* d_in, const int* in_sizes, int n_in,
                              void* d_out, int out_size, void* d_ws, size_t ws_size,
                              hipStream_t stream){
  (void)in_sizes; (void)n_in; (void)out_size; (void)ws_size;
  const float* A          = (const float*)d_in[0];
  const float* b          = (const float*)d_in[1];
  const float* coeffs     = (const float*)d_in[2];
  const float* rot_tensor = (const float*)d_in[3];
  const float* S          = (const float*)d_in[4];
  const float* G          = (const float*)d_in[5];
  const float* rho        = (const float*)d_in[6];
  const float* qneutral   = (const float*)d_in[7];
  const int* g_rot_direct = (const int*)d_in[9];
  const int* g_rot        = (const int*)d_in[10];
  const int* g_oper       = (const int*)d_in[11];
  const int* g_rep        = (const int*)d_in[12];
  const int* seg_ids      = (const int*)d_in[13];
  float* out = (float*)d_out;

  // ws layout (floats): 5.35MB scalars + fockp 32MB + C2 32MB ~= 72.5MB
  float* W         = (float*)d_ws;
  float* net       = W;                    // 500000
  float* rot_out   = W + 500000;           // 700002 (padded to 700004)
  float* ep_all    = W + 1200004;          // 2048*64
  float* ener2_a   = W + 1331076;          // 2048
  float* erep_a    = W + 1333124;          // 2048
  float* fockp_all = W + 1335172;          // 2048*4096
  float* C2_all    = W + 9723780;          // 2048*4096 (ends 18112388)

  k_netvals<<<(NSPC*16)/256, 256, 0, stream>>>(A, b, coeffs, net);
  k_rot<<<(L0C + NROTC + 255)/256, 256, 0, stream>>>(net, rot_tensor, g_rot_direct, g_rot, rot_out);
  k_coulomb<<<NMOLC, 256, 0, stream>>>(S, G, rho, qneutral, ep_all, ener2_a, erep_a);
  k_erep<<<((NREPC + 63)/64 + 255)/256, 256, 0, stream>>>(net, g_rep, seg_ids, erep_a);
  k_ns<<<NMOLC, 256, 0, stream>>>(S, g_oper, rot_out, ep_all, fockp_all, C2_all);
  k_jac<<<NMOLC, 64, 0, stream>>>(fockp_all, C2_all, ener2_a, erep_a, out);
}

// Round 14
// 512.122 us; speedup vs baseline: 3.0633x; 1.0035x over previous
//
#include <hip/hip_runtime.h>

// ---------------------------------------------------------------------------
// DFTB layer, round 13.
//  K1 netvals / K2 rot / K3 coulomb / K4 erep  (unchanged)
//  K5 k_ns  : NS S^{-1/2} (6 mm) + fockp = X F X + C2 = X E S X (4 mm)
//  K6 k_jac : split-row XOR-block Jacobi + split epilogue (r12-measured,
//             no spill). Round-13 changes INSIDE the sweep loop only:
//              - three-shear rotation (exact, 3 FMA/elem-pair vs 4 VALU)
//              - 4-way split gamma/norm chains (latency 128cy -> ~40cy)
//              - native v_rcp/v_rsq for the angle chain (self-correcting)
//              - sweeps 4 -> 3 (absmax bit-identical at 5 and 4 sweeps;
//                pre-commit: revert to 4 if absmax degrades)
// ---------------------------------------------------------------------------

#define NMOLC 2048
#define NSPC  500000
#define L0C   100000
#define NROTC 200000
#define NREPC 500000
#define MS 68   // LDS row stride for k_ns matmul buffers

// ---------------- K1: net_vals = A @ coeffs + b ----------------
__global__ __launch_bounds__(256) void k_netvals(const float* __restrict__ A,
                                                 const float* __restrict__ b,
                                                 const float* __restrict__ coeffs,
                                                 float* __restrict__ net){
  int gid = blockIdx.x * 256 + threadIdx.x;
  int row = gid >> 4;
  int l   = gid & 15;
  if (row >= NSPC) return;
  float4 c4 = reinterpret_cast<const float4*>(coeffs)[l];
  float4 a4 = reinterpret_cast<const float4*>(A)[(size_t)row * 16 + l];
  float s = a4.x*c4.x + a4.y*c4.y + a4.z*c4.z + a4.w*c4.w;
  s += __shfl_xor(s, 1, 16);
  s += __shfl_xor(s, 2, 16);
  s += __shfl_xor(s, 4, 16);
  s += __shfl_xor(s, 8, 16);
  if (l == 0) net[row] = s + b[row];
}

// ---------------- K2: rot_out = [0,1] ++ direct ++ rotated ----------------
__global__ __launch_bounds__(256) void k_rot(const float* __restrict__ net,
                                             const float* __restrict__ rot_tensor,
                                             const int* __restrict__ g_rot_direct,
                                             const int* __restrict__ g_rot,
                                             float* __restrict__ rot_out){
  int gid = blockIdx.x * 256 + threadIdx.x;
  if (gid == 0){ rot_out[0] = 0.f; rot_out[1] = 1.f; }
  if (gid < L0C){
    rot_out[2 + gid] = net[g_rot_direct[gid]];
  }
  int n = gid - L0C;
  if (n >= 0 && n < NROTC){
    float v0 = net[g_rot[3*n    ]];
    float v1 = net[g_rot[3*n + 1]];
    float v2 = net[g_rot[3*n + 2]];
    const float* R = rot_tensor + (size_t)9 * n;
    float* o = rot_out + 2 + L0C + 3*n;
    o[0] = R[0]*v0 + R[1]*v1 + R[2]*v2;
    o[1] = R[3]*v0 + R[4]*v1 + R[5]*v2;
    o[2] = R[6]*v0 + R[7]*v1 + R[8]*v2;
  }
}

// ---------------- K3: dQ, ep = G@dQ, ener2; zero erep ----------------
__global__ __launch_bounds__(256) void k_coulomb(const float* __restrict__ S,
                                                 const float* __restrict__ G,
                                                 const float* __restrict__ rho,
                                                 const float* __restrict__ qneutral,
                                                 float* __restrict__ ep_all,
                                                 float* __restrict__ ener2_a,
                                                 float* __restrict__ erep_a){
  __shared__ float sRed[256];
  __shared__ float sdQ[64];
  __shared__ float sEp[64];
  const int mol = blockIdx.x;
  const int t = threadIdx.x;
  const int i = t >> 2, q4 = t & 3;
  const float* Sm = S   + (size_t)mol * 4096;
  const float* Gm = G   + (size_t)mol * 4096;
  const float* Rm = rho + (size_t)mol * 4096;

  float acc = 0.f;
  {
    const float4* S4 = reinterpret_cast<const float4*>(Sm + i*64 + q4*16);
    const float4* R4 = reinterpret_cast<const float4*>(Rm + i*64 + q4*16);
    #pragma unroll
    for (int m = 0; m < 4; ++m){
      float4 sv = S4[m], rv = R4[m];
      acc += sv.x*rv.x + sv.y*rv.y + sv.z*rv.z + sv.w*rv.w;
    }
  }
  sRed[t] = acc; __syncthreads();
  if (t < 64) sdQ[t] = qneutral[(size_t)mol*64 + t]
                       - (sRed[4*t] + sRed[4*t+1] + sRed[4*t+2] + sRed[4*t+3]);
  __syncthreads();

  float acc2 = 0.f;
  {
    const float4* G4 = reinterpret_cast<const float4*>(Gm + i*64 + q4*16);
    #pragma unroll
    for (int m = 0; m < 4; ++m){
      float4 gv = G4[m];
      int j0 = q4*16 + m*4;
      acc2 += gv.x*sdQ[j0] + gv.y*sdQ[j0+1] + gv.z*sdQ[j0+2] + gv.w*sdQ[j0+3];
    }
  }
  sRed[t] = acc2; __syncthreads();
  if (t < 64){
    float e = sRed[4*t] + sRed[4*t+1] + sRed[4*t+2] + sRed[4*t+3];
    sEp[t] = e;
    ep_all[(size_t)mol*64 + t] = e;
  }
  __syncthreads();
  if (t == 0){
    float s = 0.f;
    for (int j = 0; j < 64; ++j) s += sdQ[j] * sEp[j];
    ener2_a[mol] = 0.5f * s;
    erep_a[mol]  = 0.f;
  }
}

// ---------------- K4: Erep segment sum (sorted seg ids) ----------------
__global__ __launch_bounds__(256) void k_erep(const float* __restrict__ net,
                                              const int* __restrict__ g_rep,
                                              const int* __restrict__ seg_ids,
                                              float* __restrict__ erep_a){
  const int CH = 64;
  long tid = (long)blockIdx.x * 256 + threadIdx.x;
  long start = tid * CH;
  if (start >= NREPC) return;
  long end = start + CH; if (end > NREPC) end = NREPC;
  int cur = seg_ids[start];
  float acc = 0.f;
  for (long e = start; e < end; ++e){
    int sgid = seg_ids[e];
    if (sgid != cur){ atomicAdd(&erep_a[cur], acc); cur = sgid; acc = 0.f; }
    acc += net[g_rep[e]];
  }
  atomicAdd(&erep_a[cur], acc);
}

// ---------------- LDS matmul helper (64x64, stride MS), A symmetric ------
__device__ __forceinline__ void mm_symA(float (*__restrict__ D)[MS],
                                        const float (*__restrict__ A)[MS],
                                        const float (*__restrict__ B)[MS],
                                        float alpha, float diag, int t){
  const int r0 = (t & 15) << 2, c0 = (t >> 4) << 2;
  float acc[4][4];
  #pragma unroll
  for (int i = 0; i < 4; ++i)
    #pragma unroll
    for (int j = 0; j < 4; ++j) acc[i][j] = 0.f;
  #pragma unroll 8
  for (int k = 0; k < 64; ++k){
    float4 av = *reinterpret_cast<const float4*>(&A[k][r0]);
    float4 bv = *reinterpret_cast<const float4*>(&B[k][c0]);
    float a_[4] = {av.x, av.y, av.z, av.w};
    float b_[4] = {bv.x, bv.y, bv.z, bv.w};
    #pragma unroll
    for (int i = 0; i < 4; ++i)
      #pragma unroll
      for (int j = 0; j < 4; ++j)
        acc[i][j] += a_[i] * b_[j];
  }
  #pragma unroll
  for (int i = 0; i < 4; ++i)
    #pragma unroll
    for (int j = 0; j < 4; ++j)
      D[r0+i][c0+j] = alpha * acc[i][j] + ((r0+i) == (c0+j) ? diag : 0.f);
}

// ---- K5: NS X=S^{-1/2} (6 mm) + fockp = X F X + C2 = X E S X (4 mm) -----
__global__ __launch_bounds__(256, 2) void k_ns(const float* __restrict__ S,
                                               const int* __restrict__ g_oper,
                                               const float* __restrict__ rot_out,
                                               const float* __restrict__ ep_all,
                                               float* __restrict__ fockp_all,
                                               float* __restrict__ C2_all){
  __shared__ float M[4][64][MS];
  __shared__ float sEp[64];
  const int t   = threadIdx.x;
  const int mol = blockIdx.x;
  const float* Sm = S + (size_t)mol * 4096;
  const int*   gm = g_oper + (size_t)mol * 4096;

  // init: M0 = S, M2 = 3I - S
  #pragma unroll
  for (int m = 0; m < 16; ++m){
    int e = t + (m << 8);
    int i = e >> 6, j = e & 63;
    float s = Sm[e];
    M[0][i][j] = s;
    M[2][i][j] = ((i == j) ? 3.f : 0.f) - s;
  }
  if (t < 64) sEp[t] = ep_all[(size_t)mol*64 + t];
  __syncthreads();
  mm_symA(M[3], M[0], M[2], 0.5f, 0.f, t);          // Y1 = 0.5 S (3I-S)
  #pragma unroll
  for (int m = 0; m < 16; ++m){
    int e = t + (m << 8);
    M[1][e >> 6][e & 63] = 0.5f * M[2][e >> 6][e & 63];  // Z1 = 0.5(3I-S)
  }
  __syncthreads();
  // iter2: Y=M3, Z=M1
  mm_symA(M[0], M[1], M[3], -1.f, 3.f, t); __syncthreads();  // T2 = 3I - Z1*Y1
  mm_symA(M[2], M[3], M[0], 0.5f, 0.f, t); __syncthreads();  // Y2 = 0.5*Y1*T2
  mm_symA(M[3], M[0], M[1], 0.5f, 0.f, t); __syncthreads();  // Z2 = 0.5*T2*Z1
  // iter3 (Z-only): Y=M2, Z=M3
  mm_symA(M[1], M[3], M[2], -1.f, 3.f, t); __syncthreads();  // T3 = 3I - Z2*Y2
  mm_symA(M[0], M[1], M[3], 0.5f, 0.f, t); __syncthreads();  // X  = 0.5*T3*Z2
  // buffers now: M0 = X; M1..M3 free

  // --- H gather -> M1 ---
  #pragma unroll
  for (int m = 0; m < 16; ++m){
    int e = t + (m << 8);
    M[1][e >> 6][e & 63] = rot_out[gm[e]];
  }
  __syncthreads();
  // --- F -> M2: F_ij = 0.5(H_ij + H_ji) - 0.5 S_ij (ep_i + ep_j) ---
  #pragma unroll
  for (int m = 0; m < 16; ++m){
    int e = t + (m << 8);
    int i = e >> 6, j = e & 63;
    M[2][i][j] = 0.5f*(M[1][i][j] + M[1][j][i]) - 0.5f*Sm[e]*(sEp[i] + sEp[j]);
  }
  __syncthreads();
  mm_symA(M[3], M[2], M[0], 1.f, 0.f, t); __syncthreads();  // P1 = F*X
  mm_symA(M[1], M[0], M[3], 1.f, 0.f, t); __syncthreads();  // fockp = X*P1
  #pragma unroll
  for (int m = 0; m < 16; ++m){
    int e = t + (m << 8);
    fockp_all[(size_t)mol * 4096 + e] = M[1][e >> 6][e & 63];
  }
  // --- reload S -> M2 ---
  #pragma unroll
  for (int m = 0; m < 16; ++m){
    int e = t + (m << 8);
    M[2][e >> 6][e & 63] = Sm[e];
  }
  __syncthreads();
  mm_symA(M[3], M[2], M[0], 1.f, 0.f, t); __syncthreads();  // C1 = S*X
  // EC1 in place: row-scale by ep
  #pragma unroll
  for (int m = 0; m < 16; ++m){
    int e = t + (m << 8);
    int i = e >> 6, j = e & 63;
    M[3][i][j] *= sEp[i];
  }
  __syncthreads();
  mm_symA(M[1], M[0], M[3], 1.f, 0.f, t); __syncthreads();  // C2 = X*(E C1)
  #pragma unroll
  for (int m = 0; m < 16; ++m){
    int e = t + (m << 8);
    C2_all[(size_t)mol * 4096 + e] = M[1][e >> 6][e & 63];
  }
}

// ---------------- K6: split-row XOR-block Jacobi + split epilogue ---------
__global__ __launch_bounds__(64, 2) void k_jac(const float* __restrict__ fockp_all,
                                               const float* __restrict__ C2_all,
                                               const float* __restrict__ ener2_a,
                                               const float* __restrict__ erep_a,
                                               float* __restrict__ out){
  __shared__ float Bl[64 * 68];         // C2 staging (pre-loaded before sweeps)
  const int lane = threadIdx.x;
  const int mol  = blockIdx.x;
  const float* Am = fockp_all + (size_t)mol * 4096;
  const float* Cm = C2_all    + (size_t)mol * 4096;
  const int pid  = lane & 31;
  const int half = lane >> 5;

  // --- direct split-layout load: proc pid = lanes (pid, pid+32);
  //     lane holds rows [half*32, half*32+32) of cols A=pid, B=32+pid ---
  float Ac[32], Bc[32];
  float csA = 0.f, csB = 0.f;
  #pragma unroll
  for (int i = 0; i < 32; ++i){
    float a = Am[(half*32 + i)*64 + pid];
    float b = Am[(half*32 + i)*64 + 32 + pid];
    Ac[i] = a; Bc[i] = b;
    csA += fabsf(a); csB += fabsf(b);
  }
  // --- stage C2 into LDS now; latency hides under the Jacobi sweeps ---
  #pragma unroll
  for (int i = 0; i < 64; ++i) Bl[i*68 + lane] = Cm[i*64 + lane];

  // --- Gershgorin shift: mu = 1.02 * max col abs-sum; add to diagonals ---
  csA += __shfl_xor(csA, 32);
  csB += __shfl_xor(csB, 32);
  float mu = fmaxf(csA, csB);
  #pragma unroll
  for (int d = 1; d < 32; d <<= 1) mu = fmaxf(mu, __shfl_xor(mu, d));
  mu *= 1.02f;
  #pragma unroll
  for (int i = 0; i < 32; ++i){
    Ac[i] += (half == 0 && i == pid) ? mu : 0.f;
    Bc[i] += (half == 1 && i == pid) ? mu : 0.f;
  }

  // --- XOR-block one-sided Jacobi (layout-invariant schedule);
  //     three-shear rotations, 4-way dot chains, native rcp/rsq ---
  for (int sweep = 0; sweep < 3; ++sweep){
    float a0 = 0.f, a1 = 0.f, a2 = 0.f, a3 = 0.f;
    float b0 = 0.f, b1 = 0.f, b2 = 0.f, b3 = 0.f;
    #pragma unroll
    for (int i = 0; i < 32; i += 4){
      a0 = fmaf(Ac[i],   Ac[i],   a0); a1 = fmaf(Ac[i+1], Ac[i+1], a1);
      a2 = fmaf(Ac[i+2], Ac[i+2], a2); a3 = fmaf(Ac[i+3], Ac[i+3], a3);
      b0 = fmaf(Bc[i],   Bc[i],   b0); b1 = fmaf(Bc[i+1], Bc[i+1], b1);
      b2 = fmaf(Bc[i+2], Bc[i+2], b2); b3 = fmaf(Bc[i+3], Bc[i+3], b3);
    }
    float alpha = (a0 + a1) + (a2 + a3);
    float beta  = (b0 + b1) + (b2 + b3);
    alpha += __shfl_xor(alpha, 32);
    beta  += __shfl_xor(beta, 32);

    unsigned long long any = 0ULL;
    for (int j = 5; j >= 0; --j){
      const int M = 1 << j;
      for (int k = 0; k < M; ++k){
        float g0 = 0.f, g1 = 0.f, g2 = 0.f, g3 = 0.f;
        #pragma unroll
        for (int i = 0; i < 32; i += 4){
          g0 = fmaf(Ac[i],   Bc[i],   g0);
          g1 = fmaf(Ac[i+1], Bc[i+1], g1);
          g2 = fmaf(Ac[i+2], Bc[i+2], g2);
          g3 = fmaf(Ac[i+3], Bc[i+3], g3);
        }
        float gamma = (g0 + g1) + (g2 + g3);
        gamma += __shfl_xor(gamma, 32);
        bool rot = (gamma * gamma) > (1e-9f * alpha * beta);
        unsigned long long bal = __ballot(rot);
        any |= bal;
        if (bal != 0ULL){
          // angle chain on native rcp/rsq (Jacobi self-corrects ULP error)
          float tau = (beta - alpha) * 0.5f * __builtin_amdgcn_rcpf(gamma);
          float tq  = copysignf(1.f, tau) *
                      __builtin_amdgcn_rcpf(fabsf(tau) + __builtin_amdgcn_sqrtf(fmaf(tau, tau, 1.f)));
          float c = __builtin_amdgcn_rsqf(fmaf(tq, tq, 1.f));
          float s = tq * c;
          float th = s * __builtin_amdgcn_rcpf(1.f + c);   // tan(theta/2)
          if (!rot){ c = 1.f; s = 0.f; th = 0.f; }
          float na = c*c*alpha + s*s*beta - 2.f*c*s*gamma;
          float nb = s*s*alpha + c*c*beta + 2.f*c*s*gamma;
          alpha = na; beta = nb;
          // three-shear rotation: exact det-1, 3 FMA per element pair
          #pragma unroll
          for (int i = 0; i < 32; ++i) Ac[i] = fmaf(-th, Bc[i], Ac[i]);
          #pragma unroll
          for (int i = 0; i < 32; ++i) Bc[i] = fmaf( s,  Ac[i], Bc[i]);
          #pragma unroll
          for (int i = 0; i < 32; ++i) Ac[i] = fmaf(-th, Bc[i], Ac[i]);
        }
        if (k < M - 1){
          int e  = k ^ (k >> 1);
          int e2 = (k + 1) ^ ((k + 1) >> 1);
          int mig = e ^ e2;
          #pragma unroll
          for (int i = 0; i < 32; ++i) Bc[i] = __shfl_xor(Bc[i], mig);
          beta = __shfl_xor(beta, mig);
        } else if (j > 0){
          const int Mp = M >> 1;
          const bool hb = (pid & Mp) != 0;
          #pragma unroll
          for (int i = 0; i < 32; ++i){
            float send = hb ? Ac[i] : Bc[i];
            float recv = __shfl_xor(send, Mp);
            Ac[i] = hb ? Bc[i] : Ac[i];
            Bc[i] = recv;
          }
          float sendb = hb ? alpha : beta;
          float recvb = __shfl_xor(sendb, Mp);
          alpha = hb ? beta : alpha;
          beta  = recvb;
        }
      }
    }
    if (any == 0ULL) break;
  }

  // --- split-form epilogue: NO reassembly, no w[64] ---
  float nA0 = 0.f, nA1 = 0.f, nB0 = 0.f, nB1 = 0.f;
  #pragma unroll
  for (int i = 0; i < 32; i += 2){
    nA0 = fmaf(Ac[i],   Ac[i],   nA0);
    nA1 = fmaf(Ac[i+1], Ac[i+1], nA1);
    nB0 = fmaf(Bc[i],   Bc[i],   nB0);
    nB1 = fmaf(Bc[i+1], Bc[i+1], nB1);
  }
  float nA = nA0 + nA1, nB = nB0 + nB1;
  nA += __shfl_xor(nA, 32);
  nB += __shfl_xor(nB, 32);
  float myLamS = half ? sqrtf(nB) : sqrtf(nA);
  float myLam  = myLamS - mu;

  int rank = 0;
  for (int k = 0; k < 64; ++k){
    float lk = __shfl(myLam, k);
    rank += (lk < myLam || (lk == myLam && k < lane)) ? 1 : 0;
  }
  out[(size_t)mol*65 + 1 + rank] = myLam;

  float occf = (rank < 32) ? 1.f : 0.f;
  float slam = occf * myLam;
  #pragma unroll
  for (int d = 1; d < 64; d <<= 1) slam += __shfl_xor(slam, d);

  // per-column scales: col A's scale lives on lane pid, col B's on lane 32+pid
  float myScale = occf / myLamS;
  float sA = __shfl(myScale, pid);
  float sB = __shfl(myScale, 32 + pid);
  #pragma unroll
  for (int i = 0; i < 32; ++i){ Ac[i] *= sA; Bc[i] *= sB; }

  __syncthreads();   // C2 staging visible (single wave: cheap)

  // quadratic form in split layout
  const int myB = half * 32;       // my row/col block offset
  const int otB = 32 - myB;        // partner block offset
  float pv[32];
  float term = 0.f;
  #pragma unroll
  for (int i = 0; i < 32; ++i) pv[i] = __shfl_xor(Ac[i], 32);
  #pragma unroll 4
  for (int i = 0; i < 32; ++i){
    const float* row = &Bl[(myB + i) * 68];
    float d = 0.f;
    #pragma unroll
    for (int k = 0; k < 32; k += 4){
      float4 c1 = *reinterpret_cast<const float4*>(&row[myB + k]);
      d = fmaf(c1.x, Ac[k], d);   d = fmaf(c1.y, Ac[k+1], d);
      d = fmaf(c1.z, Ac[k+2], d); d = fmaf(c1.w, Ac[k+3], d);
      float4 c2 = *reinterpret_cast<const float4*>(&row[otB + k]);
      d = fmaf(c2.x, pv[k], d);   d = fmaf(c2.y, pv[k+1], d);
      d = fmaf(c2.z, pv[k+2], d); d = fmaf(c2.w, pv[k+3], d);
    }
    term = fmaf(Ac[i], d, term);
  }
  #pragma unroll
  for (int i = 0; i < 32; ++i) pv[i] = __shfl_xor(Bc[i], 32);
  #pragma unroll 4
  for (int i = 0; i < 32; ++i){
    const float* row = &Bl[(myB + i) * 68];
    float d = 0.f;
    #pragma unroll
    for (int k = 0; k < 32; k += 4){
      float4 c1 = *reinterpret_cast<const float4*>(&row[myB + k]);
      d = fmaf(c1.x, Bc[k], d);   d = fmaf(c1.y, Bc[k+1], d);
      d = fmaf(c1.z, Bc[k+2], d); d = fmaf(c1.w, Bc[k+3], d);
      float4 c2 = *reinterpret_cast<const float4*>(&row[otB + k]);
      d = fmaf(c2.x, pv[k], d);   d = fmaf(c2.y, pv[k+1], d);
      d = fmaf(c2.z, pv[k+2], d); d = fmaf(c2.w, pv[k+3], d);
    }
    term = fmaf(Bc[i], d, term);
  }
  #pragma unroll
  for (int d2 = 1; d2 < 64; d2 <<= 1) term += __shfl_xor(term, d2);

  if (lane == 0){
    out[(size_t)mol*65] = 2.f*slam + 2.f*term + ener2_a[mol] + erep_a[mol];
  }
}

// ---------------------------------------------------------------------------
extern "C" void kernel_launch(void* const* d_in, const int* in_sizes, int n_in,
                              void* d_out, int out_size, void* d_ws, size_t ws_size,
                              hipStream_t stream){
  (void)in_sizes; (void)n_in; (void)out_size; (void)ws_size;
  const float* A          = (const float*)d_in[0];
  const float* b          = (const float*)d_in[1];
  const float* coeffs     = (const float*)d_in[2];
  const float* rot_tensor = (const float*)d_in[3];
  const float* S          = (const float*)d_in[4];
  const float* G          = (const float*)d_in[5];
  const float* rho        = (const float*)d_in[6];
  const float* qneutral   = (const float*)d_in[7];
  const int* g_rot_direct = (const int*)d_in[9];
  const int* g_rot        = (const int*)d_in[10];
  const int* g_oper       = (const int*)d_in[11];
  const int* g_rep        = (const int*)d_in[12];
  const int* seg_ids      = (const int*)d_in[13];
  float* out = (float*)d_out;

  // ws layout (floats): 5.35MB scalars + fockp 32MB + C2 32MB ~= 72.5MB
  float* W         = (float*)d_ws;
  float* net       = W;                    // 500000
  float* rot_out   = W + 500000;           // 700002 (padded to 700004)
  float* ep_all    = W + 1200004;          // 2048*64
  float* ener2_a   = W + 1331076;          // 2048
  float* erep_a    = W + 1333124;          // 2048
  float* fockp_all = W + 1335172;          // 2048*4096
  float* C2_all    = W + 9723780;          // 2048*4096 (ends 18112388)

  k_netvals<<<(NSPC*16)/256, 256, 0, stream>>>(A, b, coeffs, net);
  k_rot<<<(L0C + NROTC + 255)/256, 256, 0, stream>>>(net, rot_tensor, g_rot_direct, g_rot, rot_out);
  k_coulomb<<<NMOLC, 256, 0, stream>>>(S, G, rho, qneutral, ep_all, ener2_a, erep_a);
  k_erep<<<((NREPC + 63)/64 + 255)/256, 256, 0, stream>>>(net, g_rep, seg_ids, erep_a);
  k_ns<<<NMOLC, 256, 0, stream>>>(S, g_oper, rot_out, ep_all, fockp_all, C2_all);
  k_jac<<<NMOLC, 64, 0, stream>>>(fockp_all, C2_all, ener2_a, erep_a, out);
}